// Round 10
// baseline (269.716 us; speedup 1.0000x reference)
//
#include <hip/hip_runtime.h>

// Problem constants (fixed by the reference setup_inputs)
#define B_SZ 2
#define T_SZ 2048
#define DM   1024
#define NH   16
#define DH   64
#define MROWS (B_SZ * T_SZ)   // 4096

typedef unsigned short u16;
typedef short  s16x8 __attribute__((ext_vector_type(8)));   // 8 bf16 (4 VGPRs)
typedef float  f32x4 __attribute__((ext_vector_type(4)));   // MFMA C/D

// fp32 -> bf16 round-to-nearest-even
static __device__ __forceinline__ u16 f2bf(float x) {
  unsigned u = __float_as_uint(x);
  u += 0x7fffu + ((u >> 16) & 1u);
  return (u16)(u >> 16);
}

// async global->LDS, 16B per lane. LDS dest = wave-uniform base + lane*16.
static __device__ __forceinline__ void gl_lds16(const void* g, void* l) {
  __builtin_amdgcn_global_load_lds(
      (const __attribute__((address_space(1))) unsigned*)g,
      (__attribute__((address_space(3))) unsigned*)l, 16, 0, 0);
}

// ---------------------------------------------------------------------------
// One-shot f32->bf16 convert of q,k with Q pre-scaled by 0.125*log2e.
// (GEMM is linear, so scaling A == scaling the output.) grid (2048, 2).
// ---------------------------------------------------------------------------
__global__ __launch_bounds__(256)
void cvt_qk(const float* __restrict__ qf, const float* __restrict__ kf,
            u16* __restrict__ Qc, u16* __restrict__ Kc, float qscale) {
  const int z = blockIdx.y;
  const float* src = z ? kf : qf;
  u16* dst = z ? Kc : Qc;
  const float s = z ? 1.0f : qscale;
  size_t i = ((size_t)blockIdx.x * 256 + threadIdx.x) * 8;
  float4 v0 = *(const float4*)(src + i);
  float4 v1 = *(const float4*)(src + i + 4);
  ushort4 o0, o1;
  o0.x = f2bf(v0.x * s); o0.y = f2bf(v0.y * s); o0.z = f2bf(v0.z * s); o0.w = f2bf(v0.w * s);
  o1.x = f2bf(v1.x * s); o1.y = f2bf(v1.y * s); o1.z = f2bf(v1.z * s); o1.w = f2bf(v1.w * s);
  *(ushort4*)(dst + i) = o0;
  *(ushort4*)(dst + i + 4) = o1;
}

// ---------------------------------------------------------------------------
// Wt[n][k] = bf16(W[k][n]) for Wq/Wk (z selects). grid (16,16,2).
// ---------------------------------------------------------------------------
__global__ __launch_bounds__(256)
void k_cvt_T2(const float* __restrict__ Wq, const float* __restrict__ Wk,
              u16* __restrict__ Wqt, u16* __restrict__ Wkt) {
  const float* W = blockIdx.z ? Wk : Wq;
  u16* Wt = blockIdx.z ? Wkt : Wqt;
  __shared__ u16 t[64][72];
  const int n0 = blockIdx.x * 64, k0 = blockIdx.y * 64;
  const int tid = threadIdx.x;
#pragma unroll
  for (int e = 0; e < 4; ++e) {
    int c = tid + e * 256;
    int k = c >> 4, n4 = c & 15;
    float4 v = *(const float4*)(W + (size_t)(k0 + k) * DM + n0 + n4 * 4);
    t[n4 * 4 + 0][k] = f2bf(v.x);
    t[n4 * 4 + 1][k] = f2bf(v.y);
    t[n4 * 4 + 2][k] = f2bf(v.z);
    t[n4 * 4 + 3][k] = f2bf(v.w);
  }
  __syncthreads();
#pragma unroll
  for (int e = 0; e < 2; ++e) {
    int c = tid + e * 256;
    int n = c >> 3, c16 = c & 7;
    *(uint4*)(Wt + (size_t)(n0 + n) * DM + k0 + c16 * 8) = *(const uint4*)&t[n][c16 * 8];
  }
}

// ---------------------------------------------------------------------------
// Pure-bf16 projection GEMM, m97 structure (R3-verified: off the top-5).
// ---------------------------------------------------------------------------
__global__ __launch_bounds__(256)
void gemm_qk2(const u16* __restrict__ Qc, const u16* __restrict__ Kc,
              const u16* __restrict__ Wqt, const u16* __restrict__ Wkt,
              u16* __restrict__ Qp, u16* __restrict__ Kp) {
  const int z = blockIdx.z;
  const u16* A  = z ? Kc : Qc;
  const u16* Bt = z ? Wkt : Wqt;
  u16* C = z ? Kp : Qp;

  __shared__ __align__(16) u16 As[128][64];
  __shared__ __align__(16) u16 Bs[128][64];
  const int tid = threadIdx.x;
  const int lane = tid & 63, w = tid >> 6;
  const int l15 = lane & 15, q4 = lane >> 4;
  const int wm = w & 1, wn = w >> 1;
  const int m0 = blockIdx.x * 128, n0 = blockIdx.y * 128;   // x=m for XCD share

  const int srow = lane >> 3;            // 0..7 within chunk
  const int sus  = (lane & 7) ^ srow;    // swizzled source unit

  f32x4 acc[4][4] = {};

  for (int k0 = 0; k0 < DM; k0 += 64) {
    __syncthreads();
#pragma unroll
    for (int i = 0; i < 4; ++i) {
      const int c = w * 4 + i;           // chunk 0..15 (8 rows each)
      gl_lds16(A  + (size_t)(m0 + c * 8 + srow) * DM + k0 + sus * 8, &As[c * 8][0]);
      gl_lds16(Bt + (size_t)(n0 + c * 8 + srow) * DM + k0 + sus * 8, &Bs[c * 8][0]);
    }
    __syncthreads();   // compiler drains vmcnt before s_barrier
#pragma unroll
    for (int kk = 0; kk < 2; ++kk) {
      const int u = (kk * 4 + q4) ^ (l15 & 7);
      s16x8 a[4], b[4];
#pragma unroll
      for (int mi = 0; mi < 4; ++mi)
        a[mi] = *(const s16x8*)&As[wm * 64 + mi * 16 + l15][u * 8];
#pragma unroll
      for (int ni = 0; ni < 4; ++ni)
        b[ni] = *(const s16x8*)&Bs[wn * 64 + ni * 16 + l15][u * 8];
#pragma unroll
      for (int mi = 0; mi < 4; ++mi)
#pragma unroll
        for (int ni = 0; ni < 4; ++ni)
          acc[mi][ni] = __builtin_amdgcn_mfma_f32_16x16x32_bf16(a[mi], b[ni], acc[mi][ni], 0, 0, 0);
    }
  }
#pragma unroll
  for (int mi = 0; mi < 4; ++mi)
#pragma unroll
    for (int ni = 0; ni < 4; ++ni)
#pragma unroll
      for (int r = 0; r < 4; ++r) {
        int m = m0 + wm * 64 + mi * 16 + q4 * 4 + r;
        int n = n0 + wn * 64 + ni * 16 + l15;
        C[(size_t)m * DM + n] = f2bf(acc[mi][ni][r]);
      }
}

// ---------------------------------------------------------------------------
// Pass 1 v8 (R9-verified): split-K across 2 blocks, 1024 blocks = 4.0/CU.
// ---------------------------------------------------------------------------
__global__ __launch_bounds__(256)
void attn_sums_v8(const u16* __restrict__ Qb, const u16* __restrict__ Kb,
                  float* __restrict__ sumsP) {
  __shared__ __align__(16) u16 Ks[2][128][64];
  __shared__ float red[64][17];
  const int bx = blockIdx.x;
  const int x = bx & 15, half = bx >> 4;
  const int h = blockIdx.y, b = blockIdx.z;
  const int tid = threadIdx.x;
  const int lane = tid & 63, w = tid >> 6;
  const int l15 = lane & 15, q4 = lane >> 4;
  const int qts[2] = {x, 31 - x};

  const int srow = lane >> 3;            // 0..7 within 8-row chunk
  const int sus  = (lane & 7) ^ srow;    // swizzled source 16B unit
  const int x0 = q4 ^ (l15 & 7);         // swizzled read unit, logical 0..3
  const int x1 = (4 + q4) ^ (l15 & 7);   // logical 4..7

  // stage both Q tiles (head slice, 2x64 rows) into Ks[0]
#pragma unroll
  for (int e = 0; e < 4; ++e) {
    const int ch = w * 4 + e;            // 0..15
    const int tile = ch >> 3;
    const int rb = (ch & 7) * 8 + srow;
    gl_lds16(Qb + ((size_t)(b * T_SZ + qts[tile] * 64 + rb)) * DM + h * DH + sus * 8,
             &Ks[0][ch * 8][0]);
  }
  __syncthreads();
  s16x8 qf[2][2];
#pragma unroll
  for (int s = 0; s < 2; ++s) {
    qf[s][0] = *(const s16x8*)&Ks[0][s * 64 + w * 16 + l15][x0 * 8];
    qf[s][1] = *(const s16x8*)&Ks[0][s * 64 + w * 16 + l15][x1 * 8];
  }
  __syncthreads();                       // all Q reads done before K overwrite

  const u16* Kbase = Kb + ((size_t)b * T_SZ) * DM + h * DH;
  auto stageK = [&](int buf, int r) {
#pragma unroll
    for (int e = 0; e < 4; ++e) {
      const int ch = w * 4 + e;
      gl_lds16(Kbase + (size_t)(r * 128 + ch * 8 + srow) * DM + sus * 8,
               &Ks[buf][ch * 8][0]);
    }
  };

  const int last = 31 - x;
  const int R = (last + 2) >> 1;         // R in [9,16] -> both halves non-empty
  stageK(0, half);
  __syncthreads();                       // buf0 ready

  float part[2][4] = {};
  int cur = 0;
  for (int r = half; r < R; r += 2) {
    if (r + 2 < R) stageK(cur ^ 1, r + 2);   // async; drains at loop barrier
#pragma unroll
    for (int ktl = 0; ktl < 2; ++ktl) {
      const int kt = r * 2 + ktl;
      if (kt > last) continue;
#pragma unroll
      for (int s = 0; s < 2; ++s) {
        if (kt > qts[s]) continue;
        f32x4 sacc[4] = {};
#pragma unroll
        for (int ni = 0; ni < 4; ++ni) {
          s16x8 b0 = *(const s16x8*)&Ks[cur][ktl * 64 + ni * 16 + l15][x0 * 8];
          s16x8 b1 = *(const s16x8*)&Ks[cur][ktl * 64 + ni * 16 + l15][x1 * 8];
          sacc[ni] = __builtin_amdgcn_mfma_f32_16x16x32_bf16(qf[s][0], b0, sacc[ni], 0, 0, 0);
          sacc[ni] = __builtin_amdgcn_mfma_f32_16x16x32_bf16(qf[s][1], b1, sacc[ni], 0, 0, 0);
        }
        const bool diag = (kt == qts[s]);
#pragma unroll
        for (int ni = 0; ni < 4; ++ni)
#pragma unroll
          for (int rr = 0; rr < 4; ++rr) {
            int row_l = w * 16 + q4 * 4 + rr;
            int col_l = ni * 16 + l15;
            bool ok = !diag || (col_l <= row_l);
            part[s][rr] += ok ? __builtin_amdgcn_exp2f(sacc[ni][rr]) : 0.f;
          }
      }
    }
    __syncthreads();     // drains vmcnt -> next buf ready; LDS reads done
    cur ^= 1;
  }

#pragma unroll
  for (int s = 0; s < 2; ++s) {
    __syncthreads();
#pragma unroll
    for (int rr = 0; rr < 4; ++rr) red[w * 16 + q4 * 4 + rr][l15] = part[s][rr];
    __syncthreads();
    if (tid < 64) {
      float sum = 0.f;
#pragma unroll
      for (int t = 0; t < 16; ++t) sum += red[tid][t];
      sumsP[(size_t)half * (B_SZ * NH * T_SZ) +
            ((size_t)(b * NH + h)) * T_SZ + qts[s] * 64 + tid] = sum;
    }
  }
}

// ---------------------------------------------------------------------------
// invL = 1/(sumsP[0] + sumsP[1]). 65536 elems; grid 64 x 256 x float4.
// ---------------------------------------------------------------------------
__global__ __launch_bounds__(256)
void invL_combine(const float* __restrict__ sumsP, float* __restrict__ invL) {
  size_t i = ((size_t)blockIdx.x * 256 + threadIdx.x) * 4;
  float4 a = *(const float4*)(sumsP + i);
  float4 c = *(const float4*)(sumsP + (size_t)B_SZ * NH * T_SZ + i);
  float4 o;
  o.x = 1.0f / (a.x + c.x); o.y = 1.0f / (a.y + c.y);
  o.z = 1.0f / (a.z + c.z); o.w = 1.0f / (a.w + c.w);
  *(float4*)(invL + i) = o;
}

// ---------------------------------------------------------------------------
// Pass 2 v9: v8 + C-MAJOR enumeration + bijective XCD swizzle (R9 post-
// mortem: FETCH 47MB vs 16.8MB unique -- sqrt enumeration scattered blocks
// sharing a K strip across XCDs, so staging ate ~900cyc HBM latency).
// Grid 1024 flat: logical = (orig&7)*128 + (orig>>3) (bijective, 1024%8=0),
// b = logical>>9, i = logical&511. Working i<272 decode C-MAJOR:
// base(c)=c(33-c), qt = 2c + (i-base). All 32-2c blocks sharing K strip c
// are contiguous -> same XCD -> K served from its private L2 (~5 strips =
// 1.25MB << 4MB). part keeps the OLD qt-major index (ctx_reduce unchanged).
// ---------------------------------------------------------------------------
__global__ __launch_bounds__(256)
void attn_write_v9(const u16* __restrict__ Qb, const u16* __restrict__ Kb,
                   const float* __restrict__ invL, const u16* __restrict__ Vt,
                   float* __restrict__ attn, float* __restrict__ part) {
  const int logical = ((blockIdx.x & 7) << 7) | (blockIdx.x >> 3);
  const int b = logical >> 9;
  const int i = logical & 511;
  const int tid = threadIdx.x;

  if (i >= 272) {                        // zero-fill block
    const int zi = i - 272;
    int a = 0;
    while (a < 15 && (a + 1) * (31 - (a + 1)) <= zi) ++a;
    const int r = zi - a * (31 - a);
    const int n = 15 - a;
    const int qt = 2 * a + (r >= n);
    const int c = a + 1 + (r >= n ? r - n : r);
    float* outp = attn + ((size_t)b * T_SZ + (size_t)qt * 64) * T_SZ + c * 128;
    float4 z = make_float4(0.f, 0.f, 0.f, 0.f);
#pragma unroll
    for (int e = 0; e < 8; ++e) {
      int lin = tid + e * 256;
      int row = lin >> 5, c4 = lin & 31;
      *(float4*)(outp + (size_t)row * T_SZ + c4 * 4) = z;
    }
    return;
  }

  // c-major decode: base(c) = c*(33-c) <= i < base(c+1)
  int c = (int)((33.0f - sqrtf(1089.0f - 4.0f * (float)i)) * 0.5f);
  while ((c + 1) * (33 - (c + 1)) <= i) ++c;
  while (c * (33 - c) > i) --c;
  const int qt = 2 * c + (i - c * (33 - c));

  // old qt-major flat index for part (ctx_reduce expects it)
  const int s2 = (qt + 1) >> 1;
  const int iold = (qt & 1) ? s2 * s2 + c : s2 * (s2 + 1) + c;

  float* outp = attn + ((size_t)b * T_SZ + (size_t)qt * 64) * T_SZ + c * 128;

  __shared__ __align__(16) u16 Qs[2][64][64];    // 16KB; P [64][128] at tail
  __shared__ __align__(16) u16 Ks[2][128][64];   // V strip lands in Ks[cur^1] at h=15
  __shared__ float Ls[16][64];
  const int lane = tid & 63, w = tid >> 6;
  const int l15 = lane & 15, q4 = lane >> 4;

  {  // stage invL for all heads once
    int hh = tid >> 4, r4 = tid & 15;
    *(float4*)&Ls[hh][r4 * 4] =
        *(const float4*)(invL + ((size_t)(b * NH + hh)) * T_SZ + qt * 64 + r4 * 4);
  }

  const u16* Qrow = Qb + ((size_t)(b * T_SZ + qt * 64)) * DM;
  const u16* Krow = Kb + ((size_t)(b * T_SZ + c * 128)) * DM;
  const u16* Vsrc = Vt + (size_t)b * DH * T_SZ + c * 128;

  const int srow = lane >> 3;            // 0..7 within 8-row chunk
  const int sus  = (lane & 7) ^ srow;    // swizzled source unit (16B)

  auto stage = [&](int buf, int h) {
    const int hoff = h * DH;
#pragma unroll
    for (int e = 0; e < 2; ++e) {
      const int ch = w * 2 + e;
      gl_lds16(Qrow + (size_t)(ch * 8 + srow) * DM + hoff + sus * 8, &Qs[buf][ch * 8][0]);
    }
#pragma unroll
    for (int e = 0; e < 4; ++e) {
      const int ch = w * 4 + e;
      gl_lds16(Krow + (size_t)(ch * 8 + srow) * DM + hoff + sus * 8, &Ks[buf][ch * 8][0]);
    }
  };

  stage(0, 0);
  __syncthreads();                       // drain: buf0 ready

  f32x4 acc[2][4] = {};   // [ktl][ni]
  const int x0 = q4 ^ (l15 & 7);
  const int x1 = (4 + q4) ^ (l15 & 7);

  int cur = 0;
  for (int h = 0; h < NH; ++h) {
    if (h < NH - 1) {
      stage(cur ^ 1, h + 1);             // async; drains at next barrier
    } else {
      // stage V strip [64 dh][128 t] bf16 into Ks[cur^1] (flat 16KB), 16B-unit
      // swizzle: phys slot su holds logical unit f(su), f=(u&8)|((u^(dh&7))&7)
      u16* Vl = &Ks[cur ^ 1][0][0];
#pragma unroll
      for (int e = 0; e < 4; ++e) {
        const int ch = w * 4 + e;        // chunk = 4 dh-rows (1KB)
        const int dh = ch * 4 + (lane >> 4);
        const int su = lane & 15;
        const int u = (su & 8) | ((su ^ (dh & 7)) & 7);
        gl_lds16(Vsrc + (size_t)dh * T_SZ + u * 8, Vl + ch * 512);
      }
    }
    s16x8 aq0 = *(const s16x8*)&Qs[cur][w * 16 + l15][x0 * 8];
    s16x8 aq1 = *(const s16x8*)&Qs[cur][w * 16 + l15][x1 * 8];
#pragma unroll
    for (int ktl = 0; ktl < 2; ++ktl) {
      const int kt = 2 * c + ktl;
      if (kt > qt) continue;               // uniform; acc stays zero
      f32x4 sv[4] = {};
#pragma unroll
      for (int ni = 0; ni < 4; ++ni) {
        s16x8 b0 = *(const s16x8*)&Ks[cur][ktl * 64 + ni * 16 + l15][x0 * 8];
        s16x8 b1 = *(const s16x8*)&Ks[cur][ktl * 64 + ni * 16 + l15][x1 * 8];
        sv[ni] = __builtin_amdgcn_mfma_f32_16x16x32_bf16(aq0, b0, sv[ni], 0, 0, 0);
        sv[ni] = __builtin_amdgcn_mfma_f32_16x16x32_bf16(aq1, b1, sv[ni], 0, 0, 0);
      }
      if (kt == qt) {
#pragma unroll
        for (int ni = 0; ni < 4; ++ni)
#pragma unroll
          for (int r = 0; r < 4; ++r) {
            int row_l = w * 16 + q4 * 4 + r;
            int col_l = ni * 16 + l15;
            float ev = __builtin_amdgcn_exp2f(sv[ni][r]) * Ls[h][row_l];
            if (col_l <= row_l) acc[ktl][ni][r] += ev;
          }
      } else {
#pragma unroll
        for (int ni = 0; ni < 4; ++ni)
#pragma unroll
          for (int r = 0; r < 4; ++r) {
            int row_l = w * 16 + q4 * 4 + r;
            acc[ktl][ni][r] += __builtin_amdgcn_exp2f(sv[ni][r]) * Ls[h][row_l];
          }
      }
    }
    __syncthreads();     // drains vmcnt; LDS reads done; V ready at h=15
    cur ^= 1;
  }

  // Tail: V is in Ks[cur] (staged into cur^1 at h=15, then cur flipped).
  u16* Vl = &Ks[cur][0][0];
  u16* Pl = &Qs[0][0][0];   // both Q buffers dead -> P [64][128] bf16 (16KB)

  // write attn f32 + P bf16 (swizzled) to LDS
#pragma unroll
  for (int ktl = 0; ktl < 2; ++ktl)
#pragma unroll
    for (int ni = 0; ni < 4; ++ni)
#pragma unroll
      for (int r = 0; r < 4; ++r) {
        const int row_l = w * 16 + q4 * 4 + r;
        const int col = ktl * 64 + ni * 16 + l15;
        float pv = acc[ktl][ni][r] * 0.0625f;
        outp[(size_t)row_l * T_SZ + col] = pv;
        const int u = ktl * 8 + ni * 2 + (l15 >> 3);
        const int phys = (u & 8) | ((u ^ (row_l & 7)) & 7);
        Pl[row_l * 128 + phys * 8 + (l15 & 7)] = f2bf(pv);
      }
  __syncthreads();

  // ctx partial: D[m][dh] = sum_t P[m][t] * Vt[dh][t]
  f32x4 cacc[4] = {};
#pragma unroll
  for (int kc = 0; kc < 4; ++kc) {
    const int u = kc * 4 + q4;
    const int phys = (u & 8) | ((u ^ (l15 & 7)) & 7);   // row&7 == l15&7 both sides
    s16x8 pa = *(const s16x8*)&Pl[(w * 16 + l15) * 128 + phys * 8];
#pragma unroll
    for (int ni = 0; ni < 4; ++ni) {
      s16x8 vb = *(const s16x8*)&Vl[(ni * 16 + l15) * 128 + phys * 8];
      cacc[ni] = __builtin_amdgcn_mfma_f32_16x16x32_bf16(pa, vb, cacc[ni], 0, 0, 0);
    }
  }
  float* pp = part + ((size_t)iold * B_SZ + b) * (64 * DH);
#pragma unroll
  for (int ni = 0; ni < 4; ++ni)
#pragma unroll
    for (int r = 0; r < 4; ++r)
      pp[(size_t)(w * 16 + q4 * 4 + r) * DH + ni * 16 + l15] = cacc[ni][r];
}

// ---------------------------------------------------------------------------
// V projection -> bf16 V^T: Vt[b][col][t] = bf16((v @ Wv)[b*2048+t][col]).
// One block per 16 rows (256 blocks); transpose through LDS. (R10-verified)
// ---------------------------------------------------------------------------
__global__ __launch_bounds__(256)
void proj_v(const float* __restrict__ A, const float* __restrict__ W,
            u16* __restrict__ Vt) {
  __shared__ float Ws[64][68];
  __shared__ float As[16][68];
  __shared__ float tr[64][17];
  const int tid = threadIdx.x;
  const int m0 = blockIdx.x * 16;
  const int row = tid >> 4;
  const int c4  = tid & 15;
  float4 acc = make_float4(0.f, 0.f, 0.f, 0.f);

  for (int k0 = 0; k0 < DM; k0 += 64) {
    __syncthreads();
#pragma unroll
    for (int e = 0; e < 4; ++e) {
      int lin = tid + e * 256;
      int r = lin >> 4, cc = lin & 15;
      *(float4*)&Ws[r][cc * 4] = *(const float4*)(W + (size_t)(k0 + r) * DH + cc * 4);
    }
    *(float4*)&As[row][c4 * 4] = *(const float4*)(A + (size_t)(m0 + row) * DM + k0 + c4 * 4);
    __syncthreads();
#pragma unroll
    for (int kk = 0; kk < 64; ++kk) {
      float a = As[row][kk];
      float4 wv = *(const float4*)&Ws[kk][c4 * 4];
      acc.x += a * wv.x; acc.y += a * wv.y; acc.z += a * wv.z; acc.w += a * wv.w;
    }
  }
  __syncthreads();
  tr[c4 * 4 + 0][row] = acc.x;
  tr[c4 * 4 + 1][row] = acc.y;
  tr[c4 * 4 + 2][row] = acc.z;
  tr[c4 * 4 + 3][row] = acc.w;
  __syncthreads();
  const int b = m0 >> 11;
  const int t0 = m0 & 2047;
  int col = tid >> 2, tc = tid & 3;
  ushort4 o;
  o.x = f2bf(tr[col][tc * 4 + 0]);
  o.y = f2bf(tr[col][tc * 4 + 1]);
  o.z = f2bf(tr[col][tc * 4 + 2]);
  o.w = f2bf(tr[col][tc * 4 + 3]);
  *(ushort4*)(Vt + ((size_t)b * DH + col) * T_SZ + t0 + tc * 4) = o;
}

// ---------------------------------------------------------------------------
// Dedicated compact-partials reduce (R7-verified): block (mt, b) sums its
// ncc = (mt>>1)+1 chunks -- block-uniform, coalesced, L2-resident.
// ---------------------------------------------------------------------------
__global__ __launch_bounds__(256)
void ctx_reduce(const float* __restrict__ part, float* __restrict__ ctx) {
  const int mt = blockIdx.x, b = blockIdx.y;
  const int sm = (mt + 1) >> 1;
  const int base = (mt & 1) ? sm * sm : sm * (sm + 1);
  const int ncc = (mt >> 1) + 1;
  const int tid = threadIdx.x;

  float4 a[4] = {};
  for (int cc = 0; cc < ncc; ++cc) {
    const float4* p = (const float4*)(part + ((size_t)(base + cc) * B_SZ + b) * (64 * DH));
#pragma unroll
    for (int j = 0; j < 4; ++j) {
      float4 v = p[tid + j * 256];
      a[j].x += v.x; a[j].y += v.y; a[j].z += v.z; a[j].w += v.w;
    }
  }
  float4* dst = (float4*)(ctx + ((size_t)b * T_SZ + (size_t)mt * 64) * DH);
#pragma unroll
  for (int j = 0; j < 4; ++j) dst[tid + j * 256] = a[j];
}

// ---------------------------------------------------------------------------
// Wo projection v2 (R7-verified): dense ctx[4096][64], no reduce loop.
// GRID (32 m, 8 n): blocks sharing the A-band share ID%8 -> same XCD.
// ---------------------------------------------------------------------------
__global__ __launch_bounds__(256)
void gemm_wo(const float* __restrict__ ctx, const float* __restrict__ W,
             float* __restrict__ C) {
  __shared__ float As[16][132];
  __shared__ float Ws[16][132];
  const int tid = threadIdx.x;
  const int tx = tid & 15, ty = tid >> 4;
  const int m0 = blockIdx.x * 128;   // x=m for XCD share
  const int n0 = blockIdx.y * 128;

  float acc[8][8];
#pragma unroll
  for (int i = 0; i < 8; ++i)
#pragma unroll
    for (int j = 0; j < 8; ++j) acc[i][j] = 0.f;

  for (int k0 = 0; k0 < DH; k0 += 16) {
    __syncthreads();
#pragma unroll
    for (int e = 0; e < 2; ++e) {
      int lin = tid + e * 256;
      int i = lin >> 2, j4 = lin & 3;
      float4 p = *(const float4*)(ctx + (size_t)(m0 + i) * DH + k0 + j4 * 4);
      As[j4 * 4 + 0][i] = p.x;
      As[j4 * 4 + 1][i] = p.y;
      As[j4 * 4 + 2][i] = p.z;
      As[j4 * 4 + 3][i] = p.w;
    }
#pragma unroll
    for (int e = 0; e < 2; ++e) {
      int lin = tid + e * 256;
      int kk = lin >> 5, n4 = lin & 31;
      *(float4*)&Ws[kk][n4 * 4] = *(const float4*)(W + (size_t)(k0 + kk) * DM + n0 + n4 * 4);
    }
    __syncthreads();
#pragma unroll
    for (int kk = 0; kk < 16; ++kk) {
      float4 a0 = *(const float4*)&As[kk][ty * 8];
      float4 a1 = *(const float4*)&As[kk][ty * 8 + 4];
      float4 b0 = *(const float4*)&Ws[kk][tx * 8];
      float4 b1 = *(const float4*)&Ws[kk][tx * 8 + 4];
      float a[8] = {a0.x, a0.y, a0.z, a0.w, a1.x, a1.y, a1.z, a1.w};
      float b[8] = {b0.x, b0.y, b0.z, b0.w, b1.x, b1.y, b1.z, b1.w};
#pragma unroll
      for (int i = 0; i < 8; ++i)
#pragma unroll
        for (int j = 0; j < 8; ++j) acc[i][j] += a[i] * b[j];
    }
  }
#pragma unroll
  for (int i = 0; i < 8; ++i) {
    size_t m = (size_t)(m0 + ty * 8 + i);
    int n = n0 + tx * 8;
    *(float4*)(C + m * DM + n) = make_float4(acc[i][0], acc[i][1], acc[i][2], acc[i][3]);
    *(float4*)(C + m * DM + n + 4) = make_float4(acc[i][4], acc[i][5], acc[i][6], acc[i][7]);
  }
}

// ---------------------------------------------------------------------------
extern "C" void kernel_launch(void* const* d_in, const int* in_sizes, int n_in,
                              void* d_out, int out_size, void* d_ws, size_t ws_size,
                              hipStream_t stream) {
  (void)in_sizes; (void)n_in; (void)out_size; (void)ws_size;

  const float* q  = (const float*)d_in[0];
  const float* k  = (const float*)d_in[1];
  const float* v  = (const float*)d_in[2];
  // d_in[3] is the causal tril mask; causality applied analytically.
  const float* Wq = (const float*)d_in[4];
  const float* Wk = (const float*)d_in[5];
  const float* Wv = (const float*)d_in[6];
  const float* Wo = (const float*)d_in[7];

  float* out  = (float*)d_out;                      // [4096][1024]
  float* attn = out + (size_t)MROWS * DM;           // [2][2048][2048]

  // Workspace (~30 MB)
  u16*   Qb   = (u16*)d_ws;                         // [4096][1024] bf16 (Q pre-scaled by 0.125*log2e)
  u16*   Kb   = Qb + (size_t)MROWS * DM;
  u16*   Wqt  = Kb + (size_t)MROWS * DM;            // [1024][1024] bf16 (W^T)
  u16*   Wkt  = Wqt + (size_t)DM * DM;
  u16*   Vt   = Wkt + (size_t)DM * DM;              // [2][64][2048] bf16 (V^T)
  float* invL = (float*)(Vt + (size_t)B_SZ * DH * T_SZ);  // [2][16][2048] f32
  float* part = invL + (size_t)B_SZ * NH * T_SZ;    // [272][2][64][64] f32 (8.9 MB, compact)

  // bf16 copies of q,k live in the attn OUTPUT region as scratch: gemm_qk2
  // consumes them before attn_write overwrites attn (stream-ordered).
  u16* Qc = (u16*)attn;                             // [4096][1024] bf16
  u16* Kc = Qc + (size_t)MROWS * DM;

  // dense ctx [4096][64] f32 (1 MB) aliases Qb: Qb's last readers
  // (attn_sums_v8 / attn_write_v9) precede ctx_reduce in stream order.
  float* ctx = (float*)Qb;

  // partial sums [2][2][16][2048] f32 (512 KB) alias Wqt: Wqt's last reader
  // (gemm_qk2) precedes attn_sums_v8 in stream order.
  float* sumsP = (float*)Wqt;

  dim3 thr(256, 1, 1);

  // Q pre-scaled so prob = exp2(score): scale = 0.125 * log2(e)
  const float qscale = 0.125f * 1.44269504088896340736f;

  cvt_qk<<<dim3(MROWS * DM / (256 * 8), 2), thr, 0, stream>>>(q, k, Qc, Kc, qscale);
  k_cvt_T2<<<dim3(DM / 64, DM / 64, 2), thr, 0, stream>>>(Wq, Wk, Wqt, Wkt);

  gemm_qk2<<<dim3(MROWS / 128, DM / 128, 2), thr, 0, stream>>>(Qc, Kc, Wqt, Wkt, Qb, Kb);
  proj_v<<<MROWS / 16, thr, 0, stream>>>(v, Wv, Vt);

  attn_sums_v8<<<dim3(32, NH, B_SZ), thr, 0, stream>>>(Qb, Kb, sumsP);
  invL_combine<<<dim3(B_SZ * NH * T_SZ / (256 * 4)), thr, 0, stream>>>(sumsP, invL);
  attn_write_v9<<<dim3(1024), thr, 0, stream>>>(Qb, Kb, invL, Vt, attn, part);

  ctx_reduce<<<dim3(T_SZ / 64, B_SZ), thr, 0, stream>>>(part, ctx);
  gemm_wo<<<dim3(MROWS / 128, DM / 128), thr, 0, stream>>>(ctx, Wo, out);
}

// Round 11
// 252.454 us; speedup vs baseline: 1.0684x; 1.0684x over previous
//
#include <hip/hip_runtime.h>

// Problem constants (fixed by the reference setup_inputs)
#define B_SZ 2
#define T_SZ 2048
#define DM   1024
#define NH   16
#define DH   64
#define MROWS (B_SZ * T_SZ)   // 4096

typedef unsigned short u16;
typedef short  s16x8 __attribute__((ext_vector_type(8)));   // 8 bf16 (4 VGPRs)
typedef float  f32x4 __attribute__((ext_vector_type(4)));   // MFMA C/D

// fp32 -> bf16 round-to-nearest-even
static __device__ __forceinline__ u16 f2bf(float x) {
  unsigned u = __float_as_uint(x);
  u += 0x7fffu + ((u >> 16) & 1u);
  return (u16)(u >> 16);
}

// async global->LDS, 16B per lane. LDS dest = wave-uniform base + lane*16.
static __device__ __forceinline__ void gl_lds16(const void* g, void* l) {
  __builtin_amdgcn_global_load_lds(
      (const __attribute__((address_space(1))) unsigned*)g,
      (__attribute__((address_space(3))) unsigned*)l, 16, 0, 0);
}

// ---------------------------------------------------------------------------
// One-shot f32->bf16 convert of q,k with Q pre-scaled by 0.125*log2e.
// (GEMM is linear, so scaling A == scaling the output.) grid (2048, 2).
// ---------------------------------------------------------------------------
__global__ __launch_bounds__(256)
void cvt_qk(const float* __restrict__ qf, const float* __restrict__ kf,
            u16* __restrict__ Qc, u16* __restrict__ Kc, float qscale) {
  const int z = blockIdx.y;
  const float* src = z ? kf : qf;
  u16* dst = z ? Kc : Qc;
  const float s = z ? 1.0f : qscale;
  size_t i = ((size_t)blockIdx.x * 256 + threadIdx.x) * 8;
  float4 v0 = *(const float4*)(src + i);
  float4 v1 = *(const float4*)(src + i + 4);
  ushort4 o0, o1;
  o0.x = f2bf(v0.x * s); o0.y = f2bf(v0.y * s); o0.z = f2bf(v0.z * s); o0.w = f2bf(v0.w * s);
  o1.x = f2bf(v1.x * s); o1.y = f2bf(v1.y * s); o1.z = f2bf(v1.z * s); o1.w = f2bf(v1.w * s);
  *(ushort4*)(dst + i) = o0;
  *(ushort4*)(dst + i + 4) = o1;
}

// ---------------------------------------------------------------------------
// Wt[n][k] = bf16(W[k][n]) for Wq/Wk (z selects). grid (16,16,2).
// ---------------------------------------------------------------------------
__global__ __launch_bounds__(256)
void k_cvt_T2(const float* __restrict__ Wq, const float* __restrict__ Wk,
              u16* __restrict__ Wqt, u16* __restrict__ Wkt) {
  const float* W = blockIdx.z ? Wk : Wq;
  u16* Wt = blockIdx.z ? Wkt : Wqt;
  __shared__ u16 t[64][72];
  const int n0 = blockIdx.x * 64, k0 = blockIdx.y * 64;
  const int tid = threadIdx.x;
#pragma unroll
  for (int e = 0; e < 4; ++e) {
    int c = tid + e * 256;
    int k = c >> 4, n4 = c & 15;
    float4 v = *(const float4*)(W + (size_t)(k0 + k) * DM + n0 + n4 * 4);
    t[n4 * 4 + 0][k] = f2bf(v.x);
    t[n4 * 4 + 1][k] = f2bf(v.y);
    t[n4 * 4 + 2][k] = f2bf(v.z);
    t[n4 * 4 + 3][k] = f2bf(v.w);
  }
  __syncthreads();
#pragma unroll
  for (int e = 0; e < 2; ++e) {
    int c = tid + e * 256;
    int n = c >> 3, c16 = c & 7;
    *(uint4*)(Wt + (size_t)(n0 + n) * DM + k0 + c16 * 8) = *(const uint4*)&t[n][c16 * 8];
  }
}

// ---------------------------------------------------------------------------
// Pure-bf16 projection GEMM, m97 structure (R3-verified: off the top-5).
// ---------------------------------------------------------------------------
__global__ __launch_bounds__(256)
void gemm_qk2(const u16* __restrict__ Qc, const u16* __restrict__ Kc,
              const u16* __restrict__ Wqt, const u16* __restrict__ Wkt,
              u16* __restrict__ Qp, u16* __restrict__ Kp) {
  const int z = blockIdx.z;
  const u16* A  = z ? Kc : Qc;
  const u16* Bt = z ? Wkt : Wqt;
  u16* C = z ? Kp : Qp;

  __shared__ __align__(16) u16 As[128][64];
  __shared__ __align__(16) u16 Bs[128][64];
  const int tid = threadIdx.x;
  const int lane = tid & 63, w = tid >> 6;
  const int l15 = lane & 15, q4 = lane >> 4;
  const int wm = w & 1, wn = w >> 1;
  const int m0 = blockIdx.x * 128, n0 = blockIdx.y * 128;   // x=m for XCD share

  const int srow = lane >> 3;            // 0..7 within chunk
  const int sus  = (lane & 7) ^ srow;    // swizzled source unit

  f32x4 acc[4][4] = {};

  for (int k0 = 0; k0 < DM; k0 += 64) {
    __syncthreads();
#pragma unroll
    for (int i = 0; i < 4; ++i) {
      const int c = w * 4 + i;           // chunk 0..15 (8 rows each)
      gl_lds16(A  + (size_t)(m0 + c * 8 + srow) * DM + k0 + sus * 8, &As[c * 8][0]);
      gl_lds16(Bt + (size_t)(n0 + c * 8 + srow) * DM + k0 + sus * 8, &Bs[c * 8][0]);
    }
    __syncthreads();   // compiler drains vmcnt before s_barrier
#pragma unroll
    for (int kk = 0; kk < 2; ++kk) {
      const int u = (kk * 4 + q4) ^ (l15 & 7);
      s16x8 a[4], b[4];
#pragma unroll
      for (int mi = 0; mi < 4; ++mi)
        a[mi] = *(const s16x8*)&As[wm * 64 + mi * 16 + l15][u * 8];
#pragma unroll
      for (int ni = 0; ni < 4; ++ni)
        b[ni] = *(const s16x8*)&Bs[wn * 64 + ni * 16 + l15][u * 8];
#pragma unroll
      for (int mi = 0; mi < 4; ++mi)
#pragma unroll
        for (int ni = 0; ni < 4; ++ni)
          acc[mi][ni] = __builtin_amdgcn_mfma_f32_16x16x32_bf16(a[mi], b[ni], acc[mi][ni], 0, 0, 0);
    }
  }
#pragma unroll
  for (int mi = 0; mi < 4; ++mi)
#pragma unroll
    for (int ni = 0; ni < 4; ++ni)
#pragma unroll
      for (int r = 0; r < 4; ++r) {
        int m = m0 + wm * 64 + mi * 16 + q4 * 4 + r;
        int n = n0 + wn * 64 + ni * 16 + l15;
        C[(size_t)m * DM + n] = f2bf(acc[mi][ni][r]);
      }
}

// ---------------------------------------------------------------------------
// Pass 1 v8 (R9-verified): split-K across 2 blocks, 1024 blocks = 4.0/CU.
// ---------------------------------------------------------------------------
__global__ __launch_bounds__(256)
void attn_sums_v8(const u16* __restrict__ Qb, const u16* __restrict__ Kb,
                  float* __restrict__ sumsP) {
  __shared__ __align__(16) u16 Ks[2][128][64];
  __shared__ float red[64][17];
  const int bx = blockIdx.x;
  const int x = bx & 15, half = bx >> 4;
  const int h = blockIdx.y, b = blockIdx.z;
  const int tid = threadIdx.x;
  const int lane = tid & 63, w = tid >> 6;
  const int l15 = lane & 15, q4 = lane >> 4;
  const int qts[2] = {x, 31 - x};

  const int srow = lane >> 3;            // 0..7 within 8-row chunk
  const int sus  = (lane & 7) ^ srow;    // swizzled source 16B unit
  const int x0 = q4 ^ (l15 & 7);         // swizzled read unit, logical 0..3
  const int x1 = (4 + q4) ^ (l15 & 7);   // logical 4..7

  // stage both Q tiles (head slice, 2x64 rows) into Ks[0]
#pragma unroll
  for (int e = 0; e < 4; ++e) {
    const int ch = w * 4 + e;            // 0..15
    const int tile = ch >> 3;
    const int rb = (ch & 7) * 8 + srow;
    gl_lds16(Qb + ((size_t)(b * T_SZ + qts[tile] * 64 + rb)) * DM + h * DH + sus * 8,
             &Ks[0][ch * 8][0]);
  }
  __syncthreads();
  s16x8 qf[2][2];
#pragma unroll
  for (int s = 0; s < 2; ++s) {
    qf[s][0] = *(const s16x8*)&Ks[0][s * 64 + w * 16 + l15][x0 * 8];
    qf[s][1] = *(const s16x8*)&Ks[0][s * 64 + w * 16 + l15][x1 * 8];
  }
  __syncthreads();                       // all Q reads done before K overwrite

  const u16* Kbase = Kb + ((size_t)b * T_SZ) * DM + h * DH;
  auto stageK = [&](int buf, int r) {
#pragma unroll
    for (int e = 0; e < 4; ++e) {
      const int ch = w * 4 + e;
      gl_lds16(Kbase + (size_t)(r * 128 + ch * 8 + srow) * DM + sus * 8,
               &Ks[buf][ch * 8][0]);
    }
  };

  const int last = 31 - x;
  const int R = (last + 2) >> 1;         // R in [9,16] -> both halves non-empty
  stageK(0, half);
  __syncthreads();                       // buf0 ready

  float part[2][4] = {};
  int cur = 0;
  for (int r = half; r < R; r += 2) {
    if (r + 2 < R) stageK(cur ^ 1, r + 2);   // async; drains at loop barrier
#pragma unroll
    for (int ktl = 0; ktl < 2; ++ktl) {
      const int kt = r * 2 + ktl;
      if (kt > last) continue;
#pragma unroll
      for (int s = 0; s < 2; ++s) {
        if (kt > qts[s]) continue;
        f32x4 sacc[4] = {};
#pragma unroll
        for (int ni = 0; ni < 4; ++ni) {
          s16x8 b0 = *(const s16x8*)&Ks[cur][ktl * 64 + ni * 16 + l15][x0 * 8];
          s16x8 b1 = *(const s16x8*)&Ks[cur][ktl * 64 + ni * 16 + l15][x1 * 8];
          sacc[ni] = __builtin_amdgcn_mfma_f32_16x16x32_bf16(qf[s][0], b0, sacc[ni], 0, 0, 0);
          sacc[ni] = __builtin_amdgcn_mfma_f32_16x16x32_bf16(qf[s][1], b1, sacc[ni], 0, 0, 0);
        }
        const bool diag = (kt == qts[s]);
#pragma unroll
        for (int ni = 0; ni < 4; ++ni)
#pragma unroll
          for (int rr = 0; rr < 4; ++rr) {
            int row_l = w * 16 + q4 * 4 + rr;
            int col_l = ni * 16 + l15;
            bool ok = !diag || (col_l <= row_l);
            part[s][rr] += ok ? __builtin_amdgcn_exp2f(sacc[ni][rr]) : 0.f;
          }
      }
    }
    __syncthreads();     // drains vmcnt -> next buf ready; LDS reads done
    cur ^= 1;
  }

#pragma unroll
  for (int s = 0; s < 2; ++s) {
    __syncthreads();
#pragma unroll
    for (int rr = 0; rr < 4; ++rr) red[w * 16 + q4 * 4 + rr][l15] = part[s][rr];
    __syncthreads();
    if (tid < 64) {
      float sum = 0.f;
#pragma unroll
      for (int t = 0; t < 16; ++t) sum += red[tid][t];
      sumsP[(size_t)half * (B_SZ * NH * T_SZ) +
            ((size_t)(b * NH + h)) * T_SZ + qts[s] * 64 + tid] = sum;
    }
  }
}

// ---------------------------------------------------------------------------
// invL = 1/(sumsP[0] + sumsP[1]). 65536 elems; grid 64 x 256 x float4.
// ---------------------------------------------------------------------------
__global__ __launch_bounds__(256)
void invL_combine(const float* __restrict__ sumsP, float* __restrict__ invL) {
  size_t i = ((size_t)blockIdx.x * 256 + threadIdx.x) * 4;
  float4 a = *(const float4*)(sumsP + i);
  float4 c = *(const float4*)(sumsP + (size_t)B_SZ * NH * T_SZ + i);
  float4 o;
  o.x = 1.0f / (a.x + c.x); o.y = 1.0f / (a.y + c.y);
  o.z = 1.0f / (a.z + c.z); o.w = 1.0f / (a.w + c.w);
  *(float4*)(invL + i) = o;
}

// ---------------------------------------------------------------------------
// Pass 2 v10: R10 post-mortem -- v9's c-major+chunked swizzle DID fix FETCH
// (47->18.8MB) but put all working blocks on 6 of 8 XCDs (occ 17.7->9.9%,
// dur 47->60). v10 keeps locality AND balances: XCD x (= bid%8 round-robin)
// gets exactly the strip-pairs {c=x, c=15-x} of BOTH batches = 68 working
// blocks (strip sizes (32-2x)+(2+2x)=34 per batch), K footprint 4 strips
// ~1MB << 4MB L2. The 480 zero blocks are dealt 60/XCD in remaining slots.
// part keeps qt-major index (ctx_reduce unchanged). Pure mapping change.
// ---------------------------------------------------------------------------
__global__ __launch_bounds__(256)
void attn_write_v10(const u16* __restrict__ Qb, const u16* __restrict__ Kb,
                    const float* __restrict__ invL, const u16* __restrict__ Vt,
                    float* __restrict__ attn, float* __restrict__ part) {
  const int x = blockIdx.x & 7;          // XCD under round-robin dispatch
  const int slot = blockIdx.x >> 3;      // 0..127 within XCD
  const int tid = threadIdx.x;

  if (slot >= 68) {                      // zero-fill block (60 per XCD)
    const int zg = x * 60 + (slot - 68); // 0..479
    const int b = zg >= 240 ? 1 : 0;
    const int zi = zg - b * 240;
    int a = 0;
    while (a < 15 && (a + 1) * (31 - (a + 1)) <= zi) ++a;
    const int r = zi - a * (31 - a);
    const int n = 15 - a;
    const int qt = 2 * a + (r >= n);
    const int c = a + 1 + (r >= n ? r - n : r);
    float* outp = attn + ((size_t)b * T_SZ + (size_t)qt * 64) * T_SZ + c * 128;
    float4 z = make_float4(0.f, 0.f, 0.f, 0.f);
#pragma unroll
    for (int e = 0; e < 8; ++e) {
      int lin = tid + e * 256;
      int row = lin >> 5, c4 = lin & 31;
      *(float4*)(outp + (size_t)row * T_SZ + c4 * 4) = z;
    }
    return;
  }

  // working decode: slots 0..33 = batch 0 pair (c=x, c=15-x), 34..67 batch 1
  const int b = slot >= 34 ? 1 : 0;
  const int sp = slot - b * 34;          // 0..33
  const int n0 = 32 - 2 * x;             // size of strip c=x
  int c, qt;
  if (sp < n0) { c = x;      qt = 2 * x + sp; }
  else         { c = 15 - x; qt = 2 * (15 - x) + (sp - n0); }

  // qt-major flat index for part (ctx_reduce expects it)
  const int s2 = (qt + 1) >> 1;
  const int iold = (qt & 1) ? s2 * s2 + c : s2 * (s2 + 1) + c;

  float* outp = attn + ((size_t)b * T_SZ + (size_t)qt * 64) * T_SZ + c * 128;

  __shared__ __align__(16) u16 Qs[2][64][64];    // 16KB; P [64][128] at tail
  __shared__ __align__(16) u16 Ks[2][128][64];   // V strip lands in Ks[cur^1] at h=15
  __shared__ float Ls[16][64];
  const int lane = tid & 63, w = tid >> 6;
  const int l15 = lane & 15, q4 = lane >> 4;

  {  // stage invL for all heads once
    int hh = tid >> 4, r4 = tid & 15;
    *(float4*)&Ls[hh][r4 * 4] =
        *(const float4*)(invL + ((size_t)(b * NH + hh)) * T_SZ + qt * 64 + r4 * 4);
  }

  const u16* Qrow = Qb + ((size_t)(b * T_SZ + qt * 64)) * DM;
  const u16* Krow = Kb + ((size_t)(b * T_SZ + c * 128)) * DM;
  const u16* Vsrc = Vt + (size_t)b * DH * T_SZ + c * 128;

  const int srow = lane >> 3;            // 0..7 within 8-row chunk
  const int sus  = (lane & 7) ^ srow;    // swizzled source unit (16B)

  auto stage = [&](int buf, int h) {
    const int hoff = h * DH;
#pragma unroll
    for (int e = 0; e < 2; ++e) {
      const int ch = w * 2 + e;
      gl_lds16(Qrow + (size_t)(ch * 8 + srow) * DM + hoff + sus * 8, &Qs[buf][ch * 8][0]);
    }
#pragma unroll
    for (int e = 0; e < 4; ++e) {
      const int ch = w * 4 + e;
      gl_lds16(Krow + (size_t)(ch * 8 + srow) * DM + hoff + sus * 8, &Ks[buf][ch * 8][0]);
    }
  };

  stage(0, 0);
  __syncthreads();                       // drain: buf0 ready

  f32x4 acc[2][4] = {};   // [ktl][ni]
  const int x0 = q4 ^ (l15 & 7);
  const int x1 = (4 + q4) ^ (l15 & 7);

  int cur = 0;
  for (int h = 0; h < NH; ++h) {
    if (h < NH - 1) {
      stage(cur ^ 1, h + 1);             // async; drains at next barrier
    } else {
      // stage V strip [64 dh][128 t] bf16 into Ks[cur^1] (flat 16KB), 16B-unit
      // swizzle: phys slot su holds logical unit f(su), f=(u&8)|((u^(dh&7))&7)
      u16* Vl = &Ks[cur ^ 1][0][0];
#pragma unroll
      for (int e = 0; e < 4; ++e) {
        const int ch = w * 4 + e;        // chunk = 4 dh-rows (1KB)
        const int dh = ch * 4 + (lane >> 4);
        const int su = lane & 15;
        const int u = (su & 8) | ((su ^ (dh & 7)) & 7);
        gl_lds16(Vsrc + (size_t)dh * T_SZ + u * 8, Vl + ch * 512);
      }
    }
    s16x8 aq0 = *(const s16x8*)&Qs[cur][w * 16 + l15][x0 * 8];
    s16x8 aq1 = *(const s16x8*)&Qs[cur][w * 16 + l15][x1 * 8];
#pragma unroll
    for (int ktl = 0; ktl < 2; ++ktl) {
      const int kt = 2 * c + ktl;
      if (kt > qt) continue;               // uniform; acc stays zero
      f32x4 sv[4] = {};
#pragma unroll
      for (int ni = 0; ni < 4; ++ni) {
        s16x8 b0 = *(const s16x8*)&Ks[cur][ktl * 64 + ni * 16 + l15][x0 * 8];
        s16x8 b1 = *(const s16x8*)&Ks[cur][ktl * 64 + ni * 16 + l15][x1 * 8];
        sv[ni] = __builtin_amdgcn_mfma_f32_16x16x32_bf16(aq0, b0, sv[ni], 0, 0, 0);
        sv[ni] = __builtin_amdgcn_mfma_f32_16x16x32_bf16(aq1, b1, sv[ni], 0, 0, 0);
      }
      if (kt == qt) {
#pragma unroll
        for (int ni = 0; ni < 4; ++ni)
#pragma unroll
          for (int r = 0; r < 4; ++r) {
            int row_l = w * 16 + q4 * 4 + r;
            int col_l = ni * 16 + l15;
            float ev = __builtin_amdgcn_exp2f(sv[ni][r]) * Ls[h][row_l];
            if (col_l <= row_l) acc[ktl][ni][r] += ev;
          }
      } else {
#pragma unroll
        for (int ni = 0; ni < 4; ++ni)
#pragma unroll
          for (int r = 0; r < 4; ++r) {
            int row_l = w * 16 + q4 * 4 + r;
            acc[ktl][ni][r] += __builtin_amdgcn_exp2f(sv[ni][r]) * Ls[h][row_l];
          }
      }
    }
    __syncthreads();     // drains vmcnt; LDS reads done; V ready at h=15
    cur ^= 1;
  }

  // Tail: V is in Ks[cur] (staged into cur^1 at h=15, then cur flipped).
  u16* Vl = &Ks[cur][0][0];
  u16* Pl = &Qs[0][0][0];   // both Q buffers dead -> P [64][128] bf16 (16KB)

  // write attn f32 + P bf16 (swizzled) to LDS
#pragma unroll
  for (int ktl = 0; ktl < 2; ++ktl)
#pragma unroll
    for (int ni = 0; ni < 4; ++ni)
#pragma unroll
      for (int r = 0; r < 4; ++r) {
        const int row_l = w * 16 + q4 * 4 + r;
        const int col = ktl * 64 + ni * 16 + l15;
        float pv = acc[ktl][ni][r] * 0.0625f;
        outp[(size_t)row_l * T_SZ + col] = pv;
        const int u = ktl * 8 + ni * 2 + (l15 >> 3);
        const int phys = (u & 8) | ((u ^ (row_l & 7)) & 7);
        Pl[row_l * 128 + phys * 8 + (l15 & 7)] = f2bf(pv);
      }
  __syncthreads();

  // ctx partial: D[m][dh] = sum_t P[m][t] * Vt[dh][t]
  f32x4 cacc[4] = {};
#pragma unroll
  for (int kc = 0; kc < 4; ++kc) {
    const int u = kc * 4 + q4;
    const int phys = (u & 8) | ((u ^ (l15 & 7)) & 7);   // row&7 == l15&7 both sides
    s16x8 pa = *(const s16x8*)&Pl[(w * 16 + l15) * 128 + phys * 8];
#pragma unroll
    for (int ni = 0; ni < 4; ++ni) {
      s16x8 vb = *(const s16x8*)&Vl[(ni * 16 + l15) * 128 + phys * 8];
      cacc[ni] = __builtin_amdgcn_mfma_f32_16x16x32_bf16(pa, vb, cacc[ni], 0, 0, 0);
    }
  }
  float* pp = part + ((size_t)iold * B_SZ + b) * (64 * DH);
#pragma unroll
  for (int ni = 0; ni < 4; ++ni)
#pragma unroll
    for (int r = 0; r < 4; ++r)
      pp[(size_t)(w * 16 + q4 * 4 + r) * DH + ni * 16 + l15] = cacc[ni][r];
}

// ---------------------------------------------------------------------------
// V projection -> bf16 V^T: Vt[b][col][t] = bf16((v @ Wv)[b*2048+t][col]).
// One block per 16 rows (256 blocks); transpose through LDS. (R10-verified)
// ---------------------------------------------------------------------------
__global__ __launch_bounds__(256)
void proj_v(const float* __restrict__ A, const float* __restrict__ W,
            u16* __restrict__ Vt) {
  __shared__ float Ws[64][68];
  __shared__ float As[16][68];
  __shared__ float tr[64][17];
  const int tid = threadIdx.x;
  const int m0 = blockIdx.x * 16;
  const int row = tid >> 4;
  const int c4  = tid & 15;
  float4 acc = make_float4(0.f, 0.f, 0.f, 0.f);

  for (int k0 = 0; k0 < DM; k0 += 64) {
    __syncthreads();
#pragma unroll
    for (int e = 0; e < 4; ++e) {
      int lin = tid + e * 256;
      int r = lin >> 4, cc = lin & 15;
      *(float4*)&Ws[r][cc * 4] = *(const float4*)(W + (size_t)(k0 + r) * DH + cc * 4);
    }
    *(float4*)&As[row][c4 * 4] = *(const float4*)(A + (size_t)(m0 + row) * DM + k0 + c4 * 4);
    __syncthreads();
#pragma unroll
    for (int kk = 0; kk < 64; ++kk) {
      float a = As[row][kk];
      float4 wv = *(const float4*)&Ws[kk][c4 * 4];
      acc.x += a * wv.x; acc.y += a * wv.y; acc.z += a * wv.z; acc.w += a * wv.w;
    }
  }
  __syncthreads();
  tr[c4 * 4 + 0][row] = acc.x;
  tr[c4 * 4 + 1][row] = acc.y;
  tr[c4 * 4 + 2][row] = acc.z;
  tr[c4 * 4 + 3][row] = acc.w;
  __syncthreads();
  const int b = m0 >> 11;
  const int t0 = m0 & 2047;
  int col = tid >> 2, tc = tid & 3;
  ushort4 o;
  o.x = f2bf(tr[col][tc * 4 + 0]);
  o.y = f2bf(tr[col][tc * 4 + 1]);
  o.z = f2bf(tr[col][tc * 4 + 2]);
  o.w = f2bf(tr[col][tc * 4 + 3]);
  *(ushort4*)(Vt + ((size_t)b * DH + col) * T_SZ + t0 + tc * 4) = o;
}

// ---------------------------------------------------------------------------
// Dedicated compact-partials reduce (R7-verified): block (mt, b) sums its
// ncc = (mt>>1)+1 chunks -- block-uniform, coalesced, L2-resident.
// ---------------------------------------------------------------------------
__global__ __launch_bounds__(256)
void ctx_reduce(const float* __restrict__ part, float* __restrict__ ctx) {
  const int mt = blockIdx.x, b = blockIdx.y;
  const int sm = (mt + 1) >> 1;
  const int base = (mt & 1) ? sm * sm : sm * (sm + 1);
  const int ncc = (mt >> 1) + 1;
  const int tid = threadIdx.x;

  float4 a[4] = {};
  for (int cc = 0; cc < ncc; ++cc) {
    const float4* p = (const float4*)(part + ((size_t)(base + cc) * B_SZ + b) * (64 * DH));
#pragma unroll
    for (int j = 0; j < 4; ++j) {
      float4 v = p[tid + j * 256];
      a[j].x += v.x; a[j].y += v.y; a[j].z += v.z; a[j].w += v.w;
    }
  }
  float4* dst = (float4*)(ctx + ((size_t)b * T_SZ + (size_t)mt * 64) * DH);
#pragma unroll
  for (int j = 0; j < 4; ++j) dst[tid + j * 256] = a[j];
}

// ---------------------------------------------------------------------------
// Wo projection v2 (R7-verified): dense ctx[4096][64], no reduce loop.
// GRID (32 m, 8 n): blocks sharing the A-band share ID%8 -> same XCD.
// ---------------------------------------------------------------------------
__global__ __launch_bounds__(256)
void gemm_wo(const float* __restrict__ ctx, const float* __restrict__ W,
             float* __restrict__ C) {
  __shared__ float As[16][132];
  __shared__ float Ws[16][132];
  const int tid = threadIdx.x;
  const int tx = tid & 15, ty = tid >> 4;
  const int m0 = blockIdx.x * 128;   // x=m for XCD share
  const int n0 = blockIdx.y * 128;

  float acc[8][8];
#pragma unroll
  for (int i = 0; i < 8; ++i)
#pragma unroll
    for (int j = 0; j < 8; ++j) acc[i][j] = 0.f;

  for (int k0 = 0; k0 < DH; k0 += 16) {
    __syncthreads();
#pragma unroll
    for (int e = 0; e < 2; ++e) {
      int lin = tid + e * 256;
      int i = lin >> 2, j4 = lin & 3;
      float4 p = *(const float4*)(ctx + (size_t)(m0 + i) * DH + k0 + j4 * 4);
      As[j4 * 4 + 0][i] = p.x;
      As[j4 * 4 + 1][i] = p.y;
      As[j4 * 4 + 2][i] = p.z;
      As[j4 * 4 + 3][i] = p.w;
    }
#pragma unroll
    for (int e = 0; e < 2; ++e) {
      int lin = tid + e * 256;
      int kk = lin >> 5, n4 = lin & 31;
      *(float4*)&Ws[kk][n4 * 4] = *(const float4*)(W + (size_t)(k0 + kk) * DM + n0 + n4 * 4);
    }
    __syncthreads();
#pragma unroll
    for (int kk = 0; kk < 16; ++kk) {
      float4 a0 = *(const float4*)&As[kk][ty * 8];
      float4 a1 = *(const float4*)&As[kk][ty * 8 + 4];
      float4 b0 = *(const float4*)&Ws[kk][tx * 8];
      float4 b1 = *(const float4*)&Ws[kk][tx * 8 + 4];
      float a[8] = {a0.x, a0.y, a0.z, a0.w, a1.x, a1.y, a1.z, a1.w};
      float b[8] = {b0.x, b0.y, b0.z, b0.w, b1.x, b1.y, b1.z, b1.w};
#pragma unroll
      for (int i = 0; i < 8; ++i)
#pragma unroll
        for (int j = 0; j < 8; ++j) acc[i][j] += a[i] * b[j];
    }
  }
#pragma unroll
  for (int i = 0; i < 8; ++i) {
    size_t m = (size_t)(m0 + ty * 8 + i);
    int n = n0 + tx * 8;
    *(float4*)(C + m * DM + n) = make_float4(acc[i][0], acc[i][1], acc[i][2], acc[i][3]);
    *(float4*)(C + m * DM + n + 4) = make_float4(acc[i][4], acc[i][5], acc[i][6], acc[i][7]);
  }
}

// ---------------------------------------------------------------------------
extern "C" void kernel_launch(void* const* d_in, const int* in_sizes, int n_in,
                              void* d_out, int out_size, void* d_ws, size_t ws_size,
                              hipStream_t stream) {
  (void)in_sizes; (void)n_in; (void)out_size; (void)ws_size;

  const float* q  = (const float*)d_in[0];
  const float* k  = (const float*)d_in[1];
  const float* v  = (const float*)d_in[2];
  // d_in[3] is the causal tril mask; causality applied analytically.
  const float* Wq = (const float*)d_in[4];
  const float* Wk = (const float*)d_in[5];
  const float* Wv = (const float*)d_in[6];
  const float* Wo = (const float*)d_in[7];

  float* out  = (float*)d_out;                      // [4096][1024]
  float* attn = out + (size_t)MROWS * DM;           // [2][2048][2048]

  // Workspace (~30 MB)
  u16*   Qb   = (u16*)d_ws;                         // [4096][1024] bf16 (Q pre-scaled by 0.125*log2e)
  u16*   Kb   = Qb + (size_t)MROWS * DM;
  u16*   Wqt  = Kb + (size_t)MROWS * DM;            // [1024][1024] bf16 (W^T)
  u16*   Wkt  = Wqt + (size_t)DM * DM;
  u16*   Vt   = Wkt + (size_t)DM * DM;              // [2][64][2048] bf16 (V^T)
  float* invL = (float*)(Vt + (size_t)B_SZ * DH * T_SZ);  // [2][16][2048] f32
  float* part = invL + (size_t)B_SZ * NH * T_SZ;    // [272][2][64][64] f32 (8.9 MB, compact)

  // bf16 copies of q,k live in the attn OUTPUT region as scratch: gemm_qk2
  // consumes them before attn_write overwrites attn (stream-ordered).
  u16* Qc = (u16*)attn;                             // [4096][1024] bf16
  u16* Kc = Qc + (size_t)MROWS * DM;

  // dense ctx [4096][64] f32 (1 MB) aliases Qb: Qb's last readers
  // (attn_sums_v8 / attn_write_v10) precede ctx_reduce in stream order.
  float* ctx = (float*)Qb;

  // partial sums [2][2][16][2048] f32 (512 KB) alias Wqt: Wqt's last reader
  // (gemm_qk2) precedes attn_sums_v8 in stream order.
  float* sumsP = (float*)Wqt;

  dim3 thr(256, 1, 1);

  // Q pre-scaled so prob = exp2(score): scale = 0.125 * log2(e)
  const float qscale = 0.125f * 1.44269504088896340736f;

  cvt_qk<<<dim3(MROWS * DM / (256 * 8), 2), thr, 0, stream>>>(q, k, Qc, Kc, qscale);
  k_cvt_T2<<<dim3(DM / 64, DM / 64, 2), thr, 0, stream>>>(Wq, Wk, Wqt, Wkt);

  gemm_qk2<<<dim3(MROWS / 128, DM / 128, 2), thr, 0, stream>>>(Qc, Kc, Wqt, Wkt, Qb, Kb);
  proj_v<<<MROWS / 16, thr, 0, stream>>>(v, Wv, Vt);

  attn_sums_v8<<<dim3(32, NH, B_SZ), thr, 0, stream>>>(Qb, Kb, sumsP);
  invL_combine<<<dim3(B_SZ * NH * T_SZ / (256 * 4)), thr, 0, stream>>>(sumsP, invL);
  attn_write_v10<<<dim3(1024), thr, 0, stream>>>(Qb, Kb, invL, Vt, attn, part);

  ctx_reduce<<<dim3(T_SZ / 64, B_SZ), thr, 0, stream>>>(part, ctx);
  gemm_wo<<<dim3(MROWS / 128, DM / 128), thr, 0, stream>>>(ctx, Wo, out);
}

// Round 12
// 251.905 us; speedup vs baseline: 1.0707x; 1.0022x over previous
//
#include <hip/hip_runtime.h>

// Problem constants (fixed by the reference setup_inputs)
#define B_SZ 2
#define T_SZ 2048
#define DM   1024
#define NH   16
#define DH   64
#define MROWS (B_SZ * T_SZ)   // 4096

typedef unsigned short u16;
typedef short  s16x8 __attribute__((ext_vector_type(8)));   // 8 bf16 (4 VGPRs)
typedef float  f32x4 __attribute__((ext_vector_type(4)));   // MFMA C/D

// fp32 -> bf16 round-to-nearest-even
static __device__ __forceinline__ u16 f2bf(float x) {
  unsigned u = __float_as_uint(x);
  u += 0x7fffu + ((u >> 16) & 1u);
  return (u16)(u >> 16);
}

// async global->LDS, 16B per lane. LDS dest = wave-uniform base + lane*16.
static __device__ __forceinline__ void gl_lds16(const void* g, void* l) {
  __builtin_amdgcn_global_load_lds(
      (const __attribute__((address_space(1))) unsigned*)g,
      (__attribute__((address_space(3))) unsigned*)l, 16, 0, 0);
}

// ---------------------------------------------------------------------------
// One-shot f32->bf16 convert of q,k with Q pre-scaled by 0.125*log2e.
// (GEMM is linear, so scaling A == scaling the output.) grid (2048, 2).
// ---------------------------------------------------------------------------
__global__ __launch_bounds__(256)
void cvt_qk(const float* __restrict__ qf, const float* __restrict__ kf,
            u16* __restrict__ Qc, u16* __restrict__ Kc, float qscale) {
  const int z = blockIdx.y;
  const float* src = z ? kf : qf;
  u16* dst = z ? Kc : Qc;
  const float s = z ? 1.0f : qscale;
  size_t i = ((size_t)blockIdx.x * 256 + threadIdx.x) * 8;
  float4 v0 = *(const float4*)(src + i);
  float4 v1 = *(const float4*)(src + i + 4);
  ushort4 o0, o1;
  o0.x = f2bf(v0.x * s); o0.y = f2bf(v0.y * s); o0.z = f2bf(v0.z * s); o0.w = f2bf(v0.w * s);
  o1.x = f2bf(v1.x * s); o1.y = f2bf(v1.y * s); o1.z = f2bf(v1.z * s); o1.w = f2bf(v1.w * s);
  *(ushort4*)(dst + i) = o0;
  *(ushort4*)(dst + i + 4) = o1;
}

// ---------------------------------------------------------------------------
// Wt[n][k] = bf16(W[k][n]) for Wq/Wk (z selects). grid (16,16,2).
// ---------------------------------------------------------------------------
__global__ __launch_bounds__(256)
void k_cvt_T2(const float* __restrict__ Wq, const float* __restrict__ Wk,
              u16* __restrict__ Wqt, u16* __restrict__ Wkt) {
  const float* W = blockIdx.z ? Wk : Wq;
  u16* Wt = blockIdx.z ? Wkt : Wqt;
  __shared__ u16 t[64][72];
  const int n0 = blockIdx.x * 64, k0 = blockIdx.y * 64;
  const int tid = threadIdx.x;
#pragma unroll
  for (int e = 0; e < 4; ++e) {
    int c = tid + e * 256;
    int k = c >> 4, n4 = c & 15;
    float4 v = *(const float4*)(W + (size_t)(k0 + k) * DM + n0 + n4 * 4);
    t[n4 * 4 + 0][k] = f2bf(v.x);
    t[n4 * 4 + 1][k] = f2bf(v.y);
    t[n4 * 4 + 2][k] = f2bf(v.z);
    t[n4 * 4 + 3][k] = f2bf(v.w);
  }
  __syncthreads();
#pragma unroll
  for (int e = 0; e < 2; ++e) {
    int c = tid + e * 256;
    int n = c >> 3, c16 = c & 7;
    *(uint4*)(Wt + (size_t)(n0 + n) * DM + k0 + c16 * 8) = *(const uint4*)&t[n][c16 * 8];
  }
}

// ---------------------------------------------------------------------------
// Pure-bf16 projection GEMM, m97 structure (R3-verified: off the top-5).
// ---------------------------------------------------------------------------
__global__ __launch_bounds__(256)
void gemm_qk2(const u16* __restrict__ Qc, const u16* __restrict__ Kc,
              const u16* __restrict__ Wqt, const u16* __restrict__ Wkt,
              u16* __restrict__ Qp, u16* __restrict__ Kp) {
  const int z = blockIdx.z;
  const u16* A  = z ? Kc : Qc;
  const u16* Bt = z ? Wkt : Wqt;
  u16* C = z ? Kp : Qp;

  __shared__ __align__(16) u16 As[128][64];
  __shared__ __align__(16) u16 Bs[128][64];
  const int tid = threadIdx.x;
  const int lane = tid & 63, w = tid >> 6;
  const int l15 = lane & 15, q4 = lane >> 4;
  const int wm = w & 1, wn = w >> 1;
  const int m0 = blockIdx.x * 128, n0 = blockIdx.y * 128;   // x=m for XCD share

  const int srow = lane >> 3;            // 0..7 within chunk
  const int sus  = (lane & 7) ^ srow;    // swizzled source unit

  f32x4 acc[4][4] = {};

  for (int k0 = 0; k0 < DM; k0 += 64) {
    __syncthreads();
#pragma unroll
    for (int i = 0; i < 4; ++i) {
      const int c = w * 4 + i;           // chunk 0..15 (8 rows each)
      gl_lds16(A  + (size_t)(m0 + c * 8 + srow) * DM + k0 + sus * 8, &As[c * 8][0]);
      gl_lds16(Bt + (size_t)(n0 + c * 8 + srow) * DM + k0 + sus * 8, &Bs[c * 8][0]);
    }
    __syncthreads();   // compiler drains vmcnt before s_barrier
#pragma unroll
    for (int kk = 0; kk < 2; ++kk) {
      const int u = (kk * 4 + q4) ^ (l15 & 7);
      s16x8 a[4], b[4];
#pragma unroll
      for (int mi = 0; mi < 4; ++mi)
        a[mi] = *(const s16x8*)&As[wm * 64 + mi * 16 + l15][u * 8];
#pragma unroll
      for (int ni = 0; ni < 4; ++ni)
        b[ni] = *(const s16x8*)&Bs[wn * 64 + ni * 16 + l15][u * 8];
#pragma unroll
      for (int mi = 0; mi < 4; ++mi)
#pragma unroll
        for (int ni = 0; ni < 4; ++ni)
          acc[mi][ni] = __builtin_amdgcn_mfma_f32_16x16x32_bf16(a[mi], b[ni], acc[mi][ni], 0, 0, 0);
    }
  }
#pragma unroll
  for (int mi = 0; mi < 4; ++mi)
#pragma unroll
    for (int ni = 0; ni < 4; ++ni)
#pragma unroll
      for (int r = 0; r < 4; ++r) {
        int m = m0 + wm * 64 + mi * 16 + q4 * 4 + r;
        int n = n0 + wn * 64 + ni * 16 + l15;
        C[(size_t)m * DM + n] = f2bf(acc[mi][ni][r]);
      }
}

// ---------------------------------------------------------------------------
// Pass 1 v8 (R9-verified): split-K across 2 blocks, 1024 blocks = 4.0/CU.
// ---------------------------------------------------------------------------
__global__ __launch_bounds__(256)
void attn_sums_v8(const u16* __restrict__ Qb, const u16* __restrict__ Kb,
                  float* __restrict__ sumsP) {
  __shared__ __align__(16) u16 Ks[2][128][64];
  __shared__ float red[64][17];
  const int bx = blockIdx.x;
  const int x = bx & 15, half = bx >> 4;
  const int h = blockIdx.y, b = blockIdx.z;
  const int tid = threadIdx.x;
  const int lane = tid & 63, w = tid >> 6;
  const int l15 = lane & 15, q4 = lane >> 4;
  const int qts[2] = {x, 31 - x};

  const int srow = lane >> 3;            // 0..7 within 8-row chunk
  const int sus  = (lane & 7) ^ srow;    // swizzled source 16B unit
  const int x0 = q4 ^ (l15 & 7);         // swizzled read unit, logical 0..3
  const int x1 = (4 + q4) ^ (l15 & 7);   // logical 4..7

  // stage both Q tiles (head slice, 2x64 rows) into Ks[0]
#pragma unroll
  for (int e = 0; e < 4; ++e) {
    const int ch = w * 4 + e;            // 0..15
    const int tile = ch >> 3;
    const int rb = (ch & 7) * 8 + srow;
    gl_lds16(Qb + ((size_t)(b * T_SZ + qts[tile] * 64 + rb)) * DM + h * DH + sus * 8,
             &Ks[0][ch * 8][0]);
  }
  __syncthreads();
  s16x8 qf[2][2];
#pragma unroll
  for (int s = 0; s < 2; ++s) {
    qf[s][0] = *(const s16x8*)&Ks[0][s * 64 + w * 16 + l15][x0 * 8];
    qf[s][1] = *(const s16x8*)&Ks[0][s * 64 + w * 16 + l15][x1 * 8];
  }
  __syncthreads();                       // all Q reads done before K overwrite

  const u16* Kbase = Kb + ((size_t)b * T_SZ) * DM + h * DH;
  auto stageK = [&](int buf, int r) {
#pragma unroll
    for (int e = 0; e < 4; ++e) {
      const int ch = w * 4 + e;
      gl_lds16(Kbase + (size_t)(r * 128 + ch * 8 + srow) * DM + sus * 8,
               &Ks[buf][ch * 8][0]);
    }
  };

  const int last = 31 - x;
  const int R = (last + 2) >> 1;         // R in [9,16] -> both halves non-empty
  stageK(0, half);
  __syncthreads();                       // buf0 ready

  float part[2][4] = {};
  int cur = 0;
  for (int r = half; r < R; r += 2) {
    if (r + 2 < R) stageK(cur ^ 1, r + 2);   // async; drains at loop barrier
#pragma unroll
    for (int ktl = 0; ktl < 2; ++ktl) {
      const int kt = r * 2 + ktl;
      if (kt > last) continue;
#pragma unroll
      for (int s = 0; s < 2; ++s) {
        if (kt > qts[s]) continue;
        f32x4 sacc[4] = {};
#pragma unroll
        for (int ni = 0; ni < 4; ++ni) {
          s16x8 b0 = *(const s16x8*)&Ks[cur][ktl * 64 + ni * 16 + l15][x0 * 8];
          s16x8 b1 = *(const s16x8*)&Ks[cur][ktl * 64 + ni * 16 + l15][x1 * 8];
          sacc[ni] = __builtin_amdgcn_mfma_f32_16x16x32_bf16(qf[s][0], b0, sacc[ni], 0, 0, 0);
          sacc[ni] = __builtin_amdgcn_mfma_f32_16x16x32_bf16(qf[s][1], b1, sacc[ni], 0, 0, 0);
        }
        const bool diag = (kt == qts[s]);
#pragma unroll
        for (int ni = 0; ni < 4; ++ni)
#pragma unroll
          for (int rr = 0; rr < 4; ++rr) {
            int row_l = w * 16 + q4 * 4 + rr;
            int col_l = ni * 16 + l15;
            bool ok = !diag || (col_l <= row_l);
            part[s][rr] += ok ? __builtin_amdgcn_exp2f(sacc[ni][rr]) : 0.f;
          }
      }
    }
    __syncthreads();     // drains vmcnt -> next buf ready; LDS reads done
    cur ^= 1;
  }

#pragma unroll
  for (int s = 0; s < 2; ++s) {
    __syncthreads();
#pragma unroll
    for (int rr = 0; rr < 4; ++rr) red[w * 16 + q4 * 4 + rr][l15] = part[s][rr];
    __syncthreads();
    if (tid < 64) {
      float sum = 0.f;
#pragma unroll
      for (int t = 0; t < 16; ++t) sum += red[tid][t];
      sumsP[(size_t)half * (B_SZ * NH * T_SZ) +
            ((size_t)(b * NH + h)) * T_SZ + qts[s] * 64 + tid] = sum;
    }
  }
}

// ---------------------------------------------------------------------------
// invL = 1/(sumsP[0] + sumsP[1]). 65536 elems; grid 64 x 256 x float4.
// ---------------------------------------------------------------------------
__global__ __launch_bounds__(256)
void invL_combine(const float* __restrict__ sumsP, float* __restrict__ invL) {
  size_t i = ((size_t)blockIdx.x * 256 + threadIdx.x) * 4;
  float4 a = *(const float4*)(sumsP + i);
  float4 c = *(const float4*)(sumsP + (size_t)B_SZ * NH * T_SZ + i);
  float4 o;
  o.x = 1.0f / (a.x + c.x); o.y = 1.0f / (a.y + c.y);
  o.z = 1.0f / (a.z + c.z); o.w = 1.0f / (a.w + c.w);
  *(float4*)(invL + i) = o;
}

// ---------------------------------------------------------------------------
// Pass 2 v11: v10 (R11-verified: XCD pair-balance + locality) + LDS DIET.
// R11 post-mortem: 40.8us at 1.8TB/s effective, VALU 24%/Mfma 8% -- still
// latency-bound at 3 blocks/CU (53.2KB LDS). Q staging doesn't need LDS:
// each wave reads only its own 16 rows, per-lane fragments -> direct
// global->VGPR 16B loads (L2-resident after head 0; only 8 transient VGPRs,
// consumed immediately -- v5's spill held 24 across barriers). Removes Qs
// (16KB): LDS = Ks 32KB + Ls 4KB = 36.2KB -> 4 blocks/CU (+33% residency);
// stage drops 6->4 gl_lds/head. Tail P goes in the free K buffer Ks[cur^1]
// (head-15 K reads complete before the final barrier).
// ---------------------------------------------------------------------------
__global__ __launch_bounds__(256)
void attn_write_v11(const u16* __restrict__ Qb, const u16* __restrict__ Kb,
                    const float* __restrict__ invL, const u16* __restrict__ Vt,
                    float* __restrict__ attn, float* __restrict__ part) {
  const int x = blockIdx.x & 7;          // XCD under round-robin dispatch
  const int slot = blockIdx.x >> 3;      // 0..127 within XCD
  const int tid = threadIdx.x;

  if (slot >= 68) {                      // zero-fill block (60 per XCD)
    const int zg = x * 60 + (slot - 68); // 0..479
    const int b = zg >= 240 ? 1 : 0;
    const int zi = zg - b * 240;
    int a = 0;
    while (a < 15 && (a + 1) * (31 - (a + 1)) <= zi) ++a;
    const int r = zi - a * (31 - a);
    const int n = 15 - a;
    const int qt = 2 * a + (r >= n);
    const int c = a + 1 + (r >= n ? r - n : r);
    float* outp = attn + ((size_t)b * T_SZ + (size_t)qt * 64) * T_SZ + c * 128;
    float4 z = make_float4(0.f, 0.f, 0.f, 0.f);
#pragma unroll
    for (int e = 0; e < 8; ++e) {
      int lin = tid + e * 256;
      int row = lin >> 5, c4 = lin & 31;
      *(float4*)(outp + (size_t)row * T_SZ + c4 * 4) = z;
    }
    return;
  }

  // working decode: slots 0..33 = batch 0 pair (c=x, c=15-x), 34..67 batch 1
  const int b = slot >= 34 ? 1 : 0;
  const int sp = slot - b * 34;          // 0..33
  const int n0 = 32 - 2 * x;             // size of strip c=x
  int c, qt;
  if (sp < n0) { c = x;      qt = 2 * x + sp; }
  else         { c = 15 - x; qt = 2 * (15 - x) + (sp - n0); }

  // qt-major flat index for part (ctx_reduce expects it)
  const int s2 = (qt + 1) >> 1;
  const int iold = (qt & 1) ? s2 * s2 + c : s2 * (s2 + 1) + c;

  float* outp = attn + ((size_t)b * T_SZ + (size_t)qt * 64) * T_SZ + c * 128;

  __shared__ __align__(16) u16 Ks[2][128][64];   // 32KB; V + P share at tail
  __shared__ float Ls[16][64];
  const int lane = tid & 63, w = tid >> 6;
  const int l15 = lane & 15, q4 = lane >> 4;

  {  // stage invL for all heads once
    int hh = tid >> 4, r4 = tid & 15;
    *(float4*)&Ls[hh][r4 * 4] =
        *(const float4*)(invL + ((size_t)(b * NH + hh)) * T_SZ + qt * 64 + r4 * 4);
  }

  const u16* Qrow = Qb + ((size_t)(b * T_SZ + qt * 64)) * DM;
  const u16* Krow = Kb + ((size_t)(b * T_SZ + c * 128)) * DM;
  const u16* Vsrc = Vt + (size_t)b * DH * T_SZ + c * 128;

  const int srow = lane >> 3;            // 0..7 within 8-row chunk
  const int sus  = (lane & 7) ^ srow;    // swizzled source unit (16B)

  auto stageK = [&](int buf, int h) {
    const int hoff = h * DH;
#pragma unroll
    for (int e = 0; e < 4; ++e) {
      const int ch = w * 4 + e;
      gl_lds16(Krow + (size_t)(ch * 8 + srow) * DM + hoff + sus * 8, &Ks[buf][ch * 8][0]);
    }
  };

  stageK(0, 0);
  __syncthreads();                       // drain: buf0 ready

  f32x4 acc[2][4] = {};   // [ktl][ni]
  const int x0 = q4 ^ (l15 & 7);
  const int x1 = (4 + q4) ^ (l15 & 7);

  // per-lane Q fragment address base (row = w*16 + l15)
  const u16* qfrag = Qrow + (size_t)(w * 16 + l15) * DM;

  int cur = 0;
  for (int h = 0; h < NH; ++h) {
    if (h < NH - 1) {
      stageK(cur ^ 1, h + 1);            // async; drains at next barrier
    } else {
      // stage V strip [64 dh][128 t] bf16 into Ks[cur^1] (flat 16KB), 16B-unit
      // swizzle: phys slot su holds logical unit f(su), f=(u&8)|((u^(dh&7))&7)
      u16* Vl = &Ks[cur ^ 1][0][0];
#pragma unroll
      for (int e = 0; e < 4; ++e) {
        const int ch = w * 4 + e;        // chunk = 4 dh-rows (1KB)
        const int dh = ch * 4 + (lane >> 4);
        const int su = lane & 15;
        const int u = (su & 8) | ((su ^ (dh & 7)) & 7);
        gl_lds16(Vsrc + (size_t)dh * T_SZ + u * 8, Vl + ch * 512);
      }
    }
    // Q fragments: direct per-lane global loads (16B each, L2-resident)
    const int hoff = h * DH;
    s16x8 aq0 = *(const s16x8*)(qfrag + hoff + q4 * 8);
    s16x8 aq1 = *(const s16x8*)(qfrag + hoff + 32 + q4 * 8);
#pragma unroll
    for (int ktl = 0; ktl < 2; ++ktl) {
      const int kt = 2 * c + ktl;
      if (kt > qt) continue;               // uniform; acc stays zero
      f32x4 sv[4] = {};
#pragma unroll
      for (int ni = 0; ni < 4; ++ni) {
        s16x8 b0 = *(const s16x8*)&Ks[cur][ktl * 64 + ni * 16 + l15][x0 * 8];
        s16x8 b1 = *(const s16x8*)&Ks[cur][ktl * 64 + ni * 16 + l15][x1 * 8];
        sv[ni] = __builtin_amdgcn_mfma_f32_16x16x32_bf16(aq0, b0, sv[ni], 0, 0, 0);
        sv[ni] = __builtin_amdgcn_mfma_f32_16x16x32_bf16(aq1, b1, sv[ni], 0, 0, 0);
      }
      if (kt == qt) {
#pragma unroll
        for (int ni = 0; ni < 4; ++ni)
#pragma unroll
          for (int r = 0; r < 4; ++r) {
            int row_l = w * 16 + q4 * 4 + r;
            int col_l = ni * 16 + l15;
            float ev = __builtin_amdgcn_exp2f(sv[ni][r]) * Ls[h][row_l];
            if (col_l <= row_l) acc[ktl][ni][r] += ev;
          }
      } else {
#pragma unroll
        for (int ni = 0; ni < 4; ++ni)
#pragma unroll
          for (int r = 0; r < 4; ++r) {
            int row_l = w * 16 + q4 * 4 + r;
            acc[ktl][ni][r] += __builtin_amdgcn_exp2f(sv[ni][r]) * Ls[h][row_l];
          }
      }
    }
    __syncthreads();     // drains vmcnt; LDS reads done; V ready at h=15
    cur ^= 1;
  }

  // Tail: V is in Ks[cur] (staged into cur^1 at h=15, then cur flipped).
  // P goes into the OTHER K buffer (head-15's K, reads done at last barrier).
  u16* Vl = &Ks[cur][0][0];
  u16* Pl = &Ks[cur ^ 1][0][0];   // [64][128] bf16 (16KB)

  // write attn f32 + P bf16 (swizzled) to LDS
#pragma unroll
  for (int ktl = 0; ktl < 2; ++ktl)
#pragma unroll
    for (int ni = 0; ni < 4; ++ni)
#pragma unroll
      for (int r = 0; r < 4; ++r) {
        const int row_l = w * 16 + q4 * 4 + r;
        const int col = ktl * 64 + ni * 16 + l15;
        float pv = acc[ktl][ni][r] * 0.0625f;
        outp[(size_t)row_l * T_SZ + col] = pv;
        const int u = ktl * 8 + ni * 2 + (l15 >> 3);
        const int phys = (u & 8) | ((u ^ (row_l & 7)) & 7);
        Pl[row_l * 128 + phys * 8 + (l15 & 7)] = f2bf(pv);
      }
  __syncthreads();

  // ctx partial: D[m][dh] = sum_t P[m][t] * Vt[dh][t]
  f32x4 cacc[4] = {};
#pragma unroll
  for (int kc = 0; kc < 4; ++kc) {
    const int u = kc * 4 + q4;
    const int phys = (u & 8) | ((u ^ (l15 & 7)) & 7);   // row&7 == l15&7 both sides
    s16x8 pa = *(const s16x8*)&Pl[(w * 16 + l15) * 128 + phys * 8];
#pragma unroll
    for (int ni = 0; ni < 4; ++ni) {
      s16x8 vb = *(const s16x8*)&Vl[(ni * 16 + l15) * 128 + phys * 8];
      cacc[ni] = __builtin_amdgcn_mfma_f32_16x16x32_bf16(pa, vb, cacc[ni], 0, 0, 0);
    }
  }
  float* pp = part + ((size_t)iold * B_SZ + b) * (64 * DH);
#pragma unroll
  for (int ni = 0; ni < 4; ++ni)
#pragma unroll
    for (int r = 0; r < 4; ++r)
      pp[(size_t)(w * 16 + q4 * 4 + r) * DH + ni * 16 + l15] = cacc[ni][r];
}

// ---------------------------------------------------------------------------
// V projection -> bf16 V^T: Vt[b][col][t] = bf16((v @ Wv)[b*2048+t][col]).
// One block per 16 rows (256 blocks); transpose through LDS. (R10-verified)
// ---------------------------------------------------------------------------
__global__ __launch_bounds__(256)
void proj_v(const float* __restrict__ A, const float* __restrict__ W,
            u16* __restrict__ Vt) {
  __shared__ float Ws[64][68];
  __shared__ float As[16][68];
  __shared__ float tr[64][17];
  const int tid = threadIdx.x;
  const int m0 = blockIdx.x * 16;
  const int row = tid >> 4;
  const int c4  = tid & 15;
  float4 acc = make_float4(0.f, 0.f, 0.f, 0.f);

  for (int k0 = 0; k0 < DM; k0 += 64) {
    __syncthreads();
#pragma unroll
    for (int e = 0; e < 4; ++e) {
      int lin = tid + e * 256;
      int r = lin >> 4, cc = lin & 15;
      *(float4*)&Ws[r][cc * 4] = *(const float4*)(W + (size_t)(k0 + r) * DH + cc * 4);
    }
    *(float4*)&As[row][c4 * 4] = *(const float4*)(A + (size_t)(m0 + row) * DM + k0 + c4 * 4);
    __syncthreads();
#pragma unroll
    for (int kk = 0; kk < 64; ++kk) {
      float a = As[row][kk];
      float4 wv = *(const float4*)&Ws[kk][c4 * 4];
      acc.x += a * wv.x; acc.y += a * wv.y; acc.z += a * wv.z; acc.w += a * wv.w;
    }
  }
  __syncthreads();
  tr[c4 * 4 + 0][row] = acc.x;
  tr[c4 * 4 + 1][row] = acc.y;
  tr[c4 * 4 + 2][row] = acc.z;
  tr[c4 * 4 + 3][row] = acc.w;
  __syncthreads();
  const int b = m0 >> 11;
  const int t0 = m0 & 2047;
  int col = tid >> 2, tc = tid & 3;
  ushort4 o;
  o.x = f2bf(tr[col][tc * 4 + 0]);
  o.y = f2bf(tr[col][tc * 4 + 1]);
  o.z = f2bf(tr[col][tc * 4 + 2]);
  o.w = f2bf(tr[col][tc * 4 + 3]);
  *(ushort4*)(Vt + ((size_t)b * DH + col) * T_SZ + t0 + tc * 4) = o;
}

// ---------------------------------------------------------------------------
// Dedicated compact-partials reduce (R7-verified): block (mt, b) sums its
// ncc = (mt>>1)+1 chunks -- block-uniform, coalesced, L2-resident.
// ---------------------------------------------------------------------------
__global__ __launch_bounds__(256)
void ctx_reduce(const float* __restrict__ part, float* __restrict__ ctx) {
  const int mt = blockIdx.x, b = blockIdx.y;
  const int sm = (mt + 1) >> 1;
  const int base = (mt & 1) ? sm * sm : sm * (sm + 1);
  const int ncc = (mt >> 1) + 1;
  const int tid = threadIdx.x;

  float4 a[4] = {};
  for (int cc = 0; cc < ncc; ++cc) {
    const float4* p = (const float4*)(part + ((size_t)(base + cc) * B_SZ + b) * (64 * DH));
#pragma unroll
    for (int j = 0; j < 4; ++j) {
      float4 v = p[tid + j * 256];
      a[j].x += v.x; a[j].y += v.y; a[j].z += v.z; a[j].w += v.w;
    }
  }
  float4* dst = (float4*)(ctx + ((size_t)b * T_SZ + (size_t)mt * 64) * DH);
#pragma unroll
  for (int j = 0; j < 4; ++j) dst[tid + j * 256] = a[j];
}

// ---------------------------------------------------------------------------
// Wo projection v2 (R7-verified): dense ctx[4096][64], no reduce loop.
// GRID (32 m, 8 n): blocks sharing the A-band share ID%8 -> same XCD.
// ---------------------------------------------------------------------------
__global__ __launch_bounds__(256)
void gemm_wo(const float* __restrict__ ctx, const float* __restrict__ W,
             float* __restrict__ C) {
  __shared__ float As[16][132];
  __shared__ float Ws[16][132];
  const int tid = threadIdx.x;
  const int tx = tid & 15, ty = tid >> 4;
  const int m0 = blockIdx.x * 128;   // x=m for XCD share
  const int n0 = blockIdx.y * 128;

  float acc[8][8];
#pragma unroll
  for (int i = 0; i < 8; ++i)
#pragma unroll
    for (int j = 0; j < 8; ++j) acc[i][j] = 0.f;

  for (int k0 = 0; k0 < DH; k0 += 16) {
    __syncthreads();
#pragma unroll
    for (int e = 0; e < 2; ++e) {
      int lin = tid + e * 256;
      int i = lin >> 2, j4 = lin & 3;
      float4 p = *(const float4*)(ctx + (size_t)(m0 + i) * DH + k0 + j4 * 4);
      As[j4 * 4 + 0][i] = p.x;
      As[j4 * 4 + 1][i] = p.y;
      As[j4 * 4 + 2][i] = p.z;
      As[j4 * 4 + 3][i] = p.w;
    }
#pragma unroll
    for (int e = 0; e < 2; ++e) {
      int lin = tid + e * 256;
      int kk = lin >> 5, n4 = lin & 31;
      *(float4*)&Ws[kk][n4 * 4] = *(const float4*)(W + (size_t)(k0 + kk) * DM + n0 + n4 * 4);
    }
    __syncthreads();
#pragma unroll
    for (int kk = 0; kk < 16; ++kk) {
      float4 a0 = *(const float4*)&As[kk][ty * 8];
      float4 a1 = *(const float4*)&As[kk][ty * 8 + 4];
      float4 b0 = *(const float4*)&Ws[kk][tx * 8];
      float4 b1 = *(const float4*)&Ws[kk][tx * 8 + 4];
      float a[8] = {a0.x, a0.y, a0.z, a0.w, a1.x, a1.y, a1.z, a1.w};
      float b[8] = {b0.x, b0.y, b0.z, b0.w, b1.x, b1.y, b1.z, b1.w};
#pragma unroll
      for (int i = 0; i < 8; ++i)
#pragma unroll
        for (int j = 0; j < 8; ++j) acc[i][j] += a[i] * b[j];
    }
  }
#pragma unroll
  for (int i = 0; i < 8; ++i) {
    size_t m = (size_t)(m0 + ty * 8 + i);
    int n = n0 + tx * 8;
    *(float4*)(C + m * DM + n) = make_float4(acc[i][0], acc[i][1], acc[i][2], acc[i][3]);
    *(float4*)(C + m * DM + n + 4) = make_float4(acc[i][4], acc[i][5], acc[i][6], acc[i][7]);
  }
}

// ---------------------------------------------------------------------------
extern "C" void kernel_launch(void* const* d_in, const int* in_sizes, int n_in,
                              void* d_out, int out_size, void* d_ws, size_t ws_size,
                              hipStream_t stream) {
  (void)in_sizes; (void)n_in; (void)out_size; (void)ws_size;

  const float* q  = (const float*)d_in[0];
  const float* k  = (const float*)d_in[1];
  const float* v  = (const float*)d_in[2];
  // d_in[3] is the causal tril mask; causality applied analytically.
  const float* Wq = (const float*)d_in[4];
  const float* Wk = (const float*)d_in[5];
  const float* Wv = (const float*)d_in[6];
  const float* Wo = (const float*)d_in[7];

  float* out  = (float*)d_out;                      // [4096][1024]
  float* attn = out + (size_t)MROWS * DM;           // [2][2048][2048]

  // Workspace (~30 MB)
  u16*   Qb   = (u16*)d_ws;                         // [4096][1024] bf16 (Q pre-scaled by 0.125*log2e)
  u16*   Kb   = Qb + (size_t)MROWS * DM;
  u16*   Wqt  = Kb + (size_t)MROWS * DM;            // [1024][1024] bf16 (W^T)
  u16*   Wkt  = Wqt + (size_t)DM * DM;
  u16*   Vt   = Wkt + (size_t)DM * DM;              // [2][64][2048] bf16 (V^T)
  float* invL = (float*)(Vt + (size_t)B_SZ * DH * T_SZ);  // [2][16][2048] f32
  float* part = invL + (size_t)B_SZ * NH * T_SZ;    // [272][2][64][64] f32 (8.9 MB, compact)

  // bf16 copies of q,k live in the attn OUTPUT region as scratch: gemm_qk2
  // consumes them before attn_write overwrites attn (stream-ordered).
  u16* Qc = (u16*)attn;                             // [4096][1024] bf16
  u16* Kc = Qc + (size_t)MROWS * DM;

  // dense ctx [4096][64] f32 (1 MB) aliases Qb: Qb's last readers
  // (attn_sums_v8 / attn_write_v11) precede ctx_reduce in stream order.
  float* ctx = (float*)Qb;

  // partial sums [2][2][16][2048] f32 (512 KB) alias Wqt: Wqt's last reader
  // (gemm_qk2) precedes attn_sums_v8 in stream order.
  float* sumsP = (float*)Wqt;

  dim3 thr(256, 1, 1);

  // Q pre-scaled so prob = exp2(score): scale = 0.125 * log2(e)
  const float qscale = 0.125f * 1.44269504088896340736f;

  cvt_qk<<<dim3(MROWS * DM / (256 * 8), 2), thr, 0, stream>>>(q, k, Qc, Kc, qscale);
  k_cvt_T2<<<dim3(DM / 64, DM / 64, 2), thr, 0, stream>>>(Wq, Wk, Wqt, Wkt);

  gemm_qk2<<<dim3(MROWS / 128, DM / 128, 2), thr, 0, stream>>>(Qc, Kc, Wqt, Wkt, Qb, Kb);
  proj_v<<<MROWS / 16, thr, 0, stream>>>(v, Wv, Vt);

  attn_sums_v8<<<dim3(32, NH, B_SZ), thr, 0, stream>>>(Qb, Kb, sumsP);
  invL_combine<<<dim3(B_SZ * NH * T_SZ / (256 * 4)), thr, 0, stream>>>(sumsP, invL);
  attn_write_v11<<<dim3(1024), thr, 0, stream>>>(Qb, Kb, invL, Vt, attn, part);

  ctx_reduce<<<dim3(T_SZ / 64, B_SZ), thr, 0, stream>>>(part, ctx);
  gemm_wo<<<dim3(MROWS / 128, DM / 128), thr, 0, stream>>>(ctx, Wo, out);
}

// Round 13
// 250.063 us; speedup vs baseline: 1.0786x; 1.0074x over previous
//
#include <hip/hip_runtime.h>

// Problem constants (fixed by the reference setup_inputs)
#define B_SZ 2
#define T_SZ 2048
#define DM   1024
#define NH   16
#define DH   64
#define MROWS (B_SZ * T_SZ)   // 4096

typedef unsigned short u16;
typedef short  s16x8 __attribute__((ext_vector_type(8)));   // 8 bf16 (4 VGPRs)
typedef float  f32x4 __attribute__((ext_vector_type(4)));   // MFMA C/D

// fp32 -> bf16 round-to-nearest-even
static __device__ __forceinline__ u16 f2bf(float x) {
  unsigned u = __float_as_uint(x);
  u += 0x7fffu + ((u >> 16) & 1u);
  return (u16)(u >> 16);
}

// async global->LDS, 16B per lane. LDS dest = wave-uniform base + lane*16.
static __device__ __forceinline__ void gl_lds16(const void* g, void* l) {
  __builtin_amdgcn_global_load_lds(
      (const __attribute__((address_space(1))) unsigned*)g,
      (__attribute__((address_space(3))) unsigned*)l, 16, 0, 0);
}

// ---------------------------------------------------------------------------
// One-shot f32->bf16 convert of q,k with Q pre-scaled by 0.125*log2e.
// (GEMM is linear, so scaling A == scaling the output.) grid (2048, 2).
// ---------------------------------------------------------------------------
__global__ __launch_bounds__(256)
void cvt_qk(const float* __restrict__ qf, const float* __restrict__ kf,
            u16* __restrict__ Qc, u16* __restrict__ Kc, float qscale) {
  const int z = blockIdx.y;
  const float* src = z ? kf : qf;
  u16* dst = z ? Kc : Qc;
  const float s = z ? 1.0f : qscale;
  size_t i = ((size_t)blockIdx.x * 256 + threadIdx.x) * 8;
  float4 v0 = *(const float4*)(src + i);
  float4 v1 = *(const float4*)(src + i + 4);
  ushort4 o0, o1;
  o0.x = f2bf(v0.x * s); o0.y = f2bf(v0.y * s); o0.z = f2bf(v0.z * s); o0.w = f2bf(v0.w * s);
  o1.x = f2bf(v1.x * s); o1.y = f2bf(v1.y * s); o1.z = f2bf(v1.z * s); o1.w = f2bf(v1.w * s);
  *(ushort4*)(dst + i) = o0;
  *(ushort4*)(dst + i + 4) = o1;
}

// ---------------------------------------------------------------------------
// Wt[n][k] = bf16(W[k][n]) for Wq/Wk (z selects). grid (16,16,2).
// ---------------------------------------------------------------------------
__global__ __launch_bounds__(256)
void k_cvt_T2(const float* __restrict__ Wq, const float* __restrict__ Wk,
              u16* __restrict__ Wqt, u16* __restrict__ Wkt) {
  const float* W = blockIdx.z ? Wk : Wq;
  u16* Wt = blockIdx.z ? Wkt : Wqt;
  __shared__ u16 t[64][72];
  const int n0 = blockIdx.x * 64, k0 = blockIdx.y * 64;
  const int tid = threadIdx.x;
#pragma unroll
  for (int e = 0; e < 4; ++e) {
    int c = tid + e * 256;
    int k = c >> 4, n4 = c & 15;
    float4 v = *(const float4*)(W + (size_t)(k0 + k) * DM + n0 + n4 * 4);
    t[n4 * 4 + 0][k] = f2bf(v.x);
    t[n4 * 4 + 1][k] = f2bf(v.y);
    t[n4 * 4 + 2][k] = f2bf(v.z);
    t[n4 * 4 + 3][k] = f2bf(v.w);
  }
  __syncthreads();
#pragma unroll
  for (int e = 0; e < 2; ++e) {
    int c = tid + e * 256;
    int n = c >> 3, c16 = c & 7;
    *(uint4*)(Wt + (size_t)(n0 + n) * DM + k0 + c16 * 8) = *(const uint4*)&t[n][c16 * 8];
  }
}

// ---------------------------------------------------------------------------
// Pure-bf16 projection GEMM, m97 structure (R3-verified: off the top-5).
// ---------------------------------------------------------------------------
__global__ __launch_bounds__(256)
void gemm_qk2(const u16* __restrict__ Qc, const u16* __restrict__ Kc,
              const u16* __restrict__ Wqt, const u16* __restrict__ Wkt,
              u16* __restrict__ Qp, u16* __restrict__ Kp) {
  const int z = blockIdx.z;
  const u16* A  = z ? Kc : Qc;
  const u16* Bt = z ? Wkt : Wqt;
  u16* C = z ? Kp : Qp;

  __shared__ __align__(16) u16 As[128][64];
  __shared__ __align__(16) u16 Bs[128][64];
  const int tid = threadIdx.x;
  const int lane = tid & 63, w = tid >> 6;
  const int l15 = lane & 15, q4 = lane >> 4;
  const int wm = w & 1, wn = w >> 1;
  const int m0 = blockIdx.x * 128, n0 = blockIdx.y * 128;   // x=m for XCD share

  const int srow = lane >> 3;            // 0..7 within chunk
  const int sus  = (lane & 7) ^ srow;    // swizzled source unit

  f32x4 acc[4][4] = {};

  for (int k0 = 0; k0 < DM; k0 += 64) {
    __syncthreads();
#pragma unroll
    for (int i = 0; i < 4; ++i) {
      const int c = w * 4 + i;           // chunk 0..15 (8 rows each)
      gl_lds16(A  + (size_t)(m0 + c * 8 + srow) * DM + k0 + sus * 8, &As[c * 8][0]);
      gl_lds16(Bt + (size_t)(n0 + c * 8 + srow) * DM + k0 + sus * 8, &Bs[c * 8][0]);
    }
    __syncthreads();   // compiler drains vmcnt before s_barrier
#pragma unroll
    for (int kk = 0; kk < 2; ++kk) {
      const int u = (kk * 4 + q4) ^ (l15 & 7);
      s16x8 a[4], b[4];
#pragma unroll
      for (int mi = 0; mi < 4; ++mi)
        a[mi] = *(const s16x8*)&As[wm * 64 + mi * 16 + l15][u * 8];
#pragma unroll
      for (int ni = 0; ni < 4; ++ni)
        b[ni] = *(const s16x8*)&Bs[wn * 64 + ni * 16 + l15][u * 8];
#pragma unroll
      for (int mi = 0; mi < 4; ++mi)
#pragma unroll
        for (int ni = 0; ni < 4; ++ni)
          acc[mi][ni] = __builtin_amdgcn_mfma_f32_16x16x32_bf16(a[mi], b[ni], acc[mi][ni], 0, 0, 0);
    }
  }
#pragma unroll
  for (int mi = 0; mi < 4; ++mi)
#pragma unroll
    for (int ni = 0; ni < 4; ++ni)
#pragma unroll
      for (int r = 0; r < 4; ++r) {
        int m = m0 + wm * 64 + mi * 16 + q4 * 4 + r;
        int n = n0 + wn * 64 + ni * 16 + l15;
        C[(size_t)m * DM + n] = f2bf(acc[mi][ni][r]);
      }
}

// ---------------------------------------------------------------------------
// Pass 1 v8 (R9-verified): split-K across 2 blocks, 1024 blocks = 4.0/CU.
// ---------------------------------------------------------------------------
__global__ __launch_bounds__(256)
void attn_sums_v8(const u16* __restrict__ Qb, const u16* __restrict__ Kb,
                  float* __restrict__ sumsP) {
  __shared__ __align__(16) u16 Ks[2][128][64];
  __shared__ float red[64][17];
  const int bx = blockIdx.x;
  const int x = bx & 15, half = bx >> 4;
  const int h = blockIdx.y, b = blockIdx.z;
  const int tid = threadIdx.x;
  const int lane = tid & 63, w = tid >> 6;
  const int l15 = lane & 15, q4 = lane >> 4;
  const int qts[2] = {x, 31 - x};

  const int srow = lane >> 3;            // 0..7 within 8-row chunk
  const int sus  = (lane & 7) ^ srow;    // swizzled source 16B unit
  const int x0 = q4 ^ (l15 & 7);         // swizzled read unit, logical 0..3
  const int x1 = (4 + q4) ^ (l15 & 7);   // logical 4..7

  // stage both Q tiles (head slice, 2x64 rows) into Ks[0]
#pragma unroll
  for (int e = 0; e < 4; ++e) {
    const int ch = w * 4 + e;            // 0..15
    const int tile = ch >> 3;
    const int rb = (ch & 7) * 8 + srow;
    gl_lds16(Qb + ((size_t)(b * T_SZ + qts[tile] * 64 + rb)) * DM + h * DH + sus * 8,
             &Ks[0][ch * 8][0]);
  }
  __syncthreads();
  s16x8 qf[2][2];
#pragma unroll
  for (int s = 0; s < 2; ++s) {
    qf[s][0] = *(const s16x8*)&Ks[0][s * 64 + w * 16 + l15][x0 * 8];
    qf[s][1] = *(const s16x8*)&Ks[0][s * 64 + w * 16 + l15][x1 * 8];
  }
  __syncthreads();                       // all Q reads done before K overwrite

  const u16* Kbase = Kb + ((size_t)b * T_SZ) * DM + h * DH;
  auto stageK = [&](int buf, int r) {
#pragma unroll
    for (int e = 0; e < 4; ++e) {
      const int ch = w * 4 + e;
      gl_lds16(Kbase + (size_t)(r * 128 + ch * 8 + srow) * DM + sus * 8,
               &Ks[buf][ch * 8][0]);
    }
  };

  const int last = 31 - x;
  const int R = (last + 2) >> 1;         // R in [9,16] -> both halves non-empty
  stageK(0, half);
  __syncthreads();                       // buf0 ready

  float part[2][4] = {};
  int cur = 0;
  for (int r = half; r < R; r += 2) {
    if (r + 2 < R) stageK(cur ^ 1, r + 2);   // async; drains at loop barrier
#pragma unroll
    for (int ktl = 0; ktl < 2; ++ktl) {
      const int kt = r * 2 + ktl;
      if (kt > last) continue;
#pragma unroll
      for (int s = 0; s < 2; ++s) {
        if (kt > qts[s]) continue;
        f32x4 sacc[4] = {};
#pragma unroll
        for (int ni = 0; ni < 4; ++ni) {
          s16x8 b0 = *(const s16x8*)&Ks[cur][ktl * 64 + ni * 16 + l15][x0 * 8];
          s16x8 b1 = *(const s16x8*)&Ks[cur][ktl * 64 + ni * 16 + l15][x1 * 8];
          sacc[ni] = __builtin_amdgcn_mfma_f32_16x16x32_bf16(qf[s][0], b0, sacc[ni], 0, 0, 0);
          sacc[ni] = __builtin_amdgcn_mfma_f32_16x16x32_bf16(qf[s][1], b1, sacc[ni], 0, 0, 0);
        }
        const bool diag = (kt == qts[s]);
#pragma unroll
        for (int ni = 0; ni < 4; ++ni)
#pragma unroll
          for (int rr = 0; rr < 4; ++rr) {
            int row_l = w * 16 + q4 * 4 + rr;
            int col_l = ni * 16 + l15;
            bool ok = !diag || (col_l <= row_l);
            part[s][rr] += ok ? __builtin_amdgcn_exp2f(sacc[ni][rr]) : 0.f;
          }
      }
    }
    __syncthreads();     // drains vmcnt -> next buf ready; LDS reads done
    cur ^= 1;
  }

#pragma unroll
  for (int s = 0; s < 2; ++s) {
    __syncthreads();
#pragma unroll
    for (int rr = 0; rr < 4; ++rr) red[w * 16 + q4 * 4 + rr][l15] = part[s][rr];
    __syncthreads();
    if (tid < 64) {
      float sum = 0.f;
#pragma unroll
      for (int t = 0; t < 16; ++t) sum += red[tid][t];
      sumsP[(size_t)half * (B_SZ * NH * T_SZ) +
            ((size_t)(b * NH + h)) * T_SZ + qts[s] * 64 + tid] = sum;
    }
  }
}

// ---------------------------------------------------------------------------
// invL = 1/(sumsP[0] + sumsP[1]). 65536 elems; grid 64 x 256 x float4.
// ---------------------------------------------------------------------------
__global__ __launch_bounds__(256)
void invL_combine(const float* __restrict__ sumsP, float* __restrict__ invL) {
  size_t i = ((size_t)blockIdx.x * 256 + threadIdx.x) * 4;
  float4 a = *(const float4*)(sumsP + i);
  float4 c = *(const float4*)(sumsP + (size_t)B_SZ * NH * T_SZ + i);
  float4 o;
  o.x = 1.0f / (a.x + c.x); o.y = 1.0f / (a.y + c.y);
  o.z = 1.0f / (a.z + c.z); o.w = 1.0f / (a.w + c.w);
  *(float4*)(invL + i) = o;
}

// ---------------------------------------------------------------------------
// Pass 2 v12: v11 + REGISTER Q double-buffer. R12 post-mortem: v11's LDS
// diet landed (36.8KB, 4 blocks/CU possible) but dur was flat -- v11 also
// moved the Q fragment load onto the critical path (per-lane GLOBAL load at
// the top of each head's compute; v10 had it in LDS a head ahead). Fix:
// load head h+1's two s16x8 Q fragments right after issuing h+1's K stage;
// consume next iteration. L2 latency hides under head h's MFMA+exp2. Only
// 8 VGPRs held across ONE barrier (v5's spill: 24 across two, tighter
// budget). __syncthreads is a full fence -> loads can't sink past it.
// ---------------------------------------------------------------------------
__global__ __launch_bounds__(256)
void attn_write_v12(const u16* __restrict__ Qb, const u16* __restrict__ Kb,
                    const float* __restrict__ invL, const u16* __restrict__ Vt,
                    float* __restrict__ attn, float* __restrict__ part) {
  const int x = blockIdx.x & 7;          // XCD under round-robin dispatch
  const int slot = blockIdx.x >> 3;      // 0..127 within XCD
  const int tid = threadIdx.x;

  if (slot >= 68) {                      // zero-fill block (60 per XCD)
    const int zg = x * 60 + (slot - 68); // 0..479
    const int b = zg >= 240 ? 1 : 0;
    const int zi = zg - b * 240;
    int a = 0;
    while (a < 15 && (a + 1) * (31 - (a + 1)) <= zi) ++a;
    const int r = zi - a * (31 - a);
    const int n = 15 - a;
    const int qt = 2 * a + (r >= n);
    const int c = a + 1 + (r >= n ? r - n : r);
    float* outp = attn + ((size_t)b * T_SZ + (size_t)qt * 64) * T_SZ + c * 128;
    float4 z = make_float4(0.f, 0.f, 0.f, 0.f);
#pragma unroll
    for (int e = 0; e < 8; ++e) {
      int lin = tid + e * 256;
      int row = lin >> 5, c4 = lin & 31;
      *(float4*)(outp + (size_t)row * T_SZ + c4 * 4) = z;
    }
    return;
  }

  // working decode: slots 0..33 = batch 0 pair (c=x, c=15-x), 34..67 batch 1
  const int b = slot >= 34 ? 1 : 0;
  const int sp = slot - b * 34;          // 0..33
  const int n0 = 32 - 2 * x;             // size of strip c=x
  int c, qt;
  if (sp < n0) { c = x;      qt = 2 * x + sp; }
  else         { c = 15 - x; qt = 2 * (15 - x) + (sp - n0); }

  // qt-major flat index for part (ctx_reduce expects it)
  const int s2 = (qt + 1) >> 1;
  const int iold = (qt & 1) ? s2 * s2 + c : s2 * (s2 + 1) + c;

  float* outp = attn + ((size_t)b * T_SZ + (size_t)qt * 64) * T_SZ + c * 128;

  __shared__ __align__(16) u16 Ks[2][128][64];   // 32KB; V + P share at tail
  __shared__ float Ls[16][64];
  const int lane = tid & 63, w = tid >> 6;
  const int l15 = lane & 15, q4 = lane >> 4;

  {  // stage invL for all heads once
    int hh = tid >> 4, r4 = tid & 15;
    *(float4*)&Ls[hh][r4 * 4] =
        *(const float4*)(invL + ((size_t)(b * NH + hh)) * T_SZ + qt * 64 + r4 * 4);
  }

  const u16* Qrow = Qb + ((size_t)(b * T_SZ + qt * 64)) * DM;
  const u16* Krow = Kb + ((size_t)(b * T_SZ + c * 128)) * DM;
  const u16* Vsrc = Vt + (size_t)b * DH * T_SZ + c * 128;

  const int srow = lane >> 3;            // 0..7 within 8-row chunk
  const int sus  = (lane & 7) ^ srow;    // swizzled source unit (16B)

  auto stageK = [&](int buf, int h) {
    const int hoff = h * DH;
#pragma unroll
    for (int e = 0; e < 4; ++e) {
      const int ch = w * 4 + e;
      gl_lds16(Krow + (size_t)(ch * 8 + srow) * DM + hoff + sus * 8, &Ks[buf][ch * 8][0]);
    }
  };

  stageK(0, 0);

  f32x4 acc[2][4] = {};   // [ktl][ni]
  const int x0 = q4 ^ (l15 & 7);
  const int x1 = (4 + q4) ^ (l15 & 7);

  // per-lane Q fragment address base (row = w*16 + l15)
  const u16* qfrag = Qrow + (size_t)(w * 16 + l15) * DM;

  // preload head 0's Q fragments (overlaps the K stage + barrier)
  s16x8 q0 = *(const s16x8*)(qfrag + q4 * 8);
  s16x8 q1 = *(const s16x8*)(qfrag + 32 + q4 * 8);

  __syncthreads();                       // drain: buf0 + q0/q1 ready

  int cur = 0;
  for (int h = 0; h < NH; ++h) {
    s16x8 nq0 = q0, nq1 = q1;
    if (h < NH - 1) {
      stageK(cur ^ 1, h + 1);            // async; drains at next barrier
      const int nhoff = (h + 1) * DH;    // Q prefetch: latency hides under
      nq0 = *(const s16x8*)(qfrag + nhoff + q4 * 8);        // this head's
      nq1 = *(const s16x8*)(qfrag + nhoff + 32 + q4 * 8);   // MFMA+exp2
    } else {
      // stage V strip [64 dh][128 t] bf16 into Ks[cur^1] (flat 16KB), 16B-unit
      // swizzle: phys slot su holds logical unit f(su), f=(u&8)|((u^(dh&7))&7)
      u16* Vl = &Ks[cur ^ 1][0][0];
#pragma unroll
      for (int e = 0; e < 4; ++e) {
        const int ch = w * 4 + e;        // chunk = 4 dh-rows (1KB)
        const int dh = ch * 4 + (lane >> 4);
        const int su = lane & 15;
        const int u = (su & 8) | ((su ^ (dh & 7)) & 7);
        gl_lds16(Vsrc + (size_t)dh * T_SZ + u * 8, Vl + ch * 512);
      }
    }
#pragma unroll
    for (int ktl = 0; ktl < 2; ++ktl) {
      const int kt = 2 * c + ktl;
      if (kt > qt) continue;               // uniform; acc stays zero
      f32x4 sv[4] = {};
#pragma unroll
      for (int ni = 0; ni < 4; ++ni) {
        s16x8 b0 = *(const s16x8*)&Ks[cur][ktl * 64 + ni * 16 + l15][x0 * 8];
        s16x8 b1 = *(const s16x8*)&Ks[cur][ktl * 64 + ni * 16 + l15][x1 * 8];
        sv[ni] = __builtin_amdgcn_mfma_f32_16x16x32_bf16(q0, b0, sv[ni], 0, 0, 0);
        sv[ni] = __builtin_amdgcn_mfma_f32_16x16x32_bf16(q1, b1, sv[ni], 0, 0, 0);
      }
      if (kt == qt) {
#pragma unroll
        for (int ni = 0; ni < 4; ++ni)
#pragma unroll
          for (int r = 0; r < 4; ++r) {
            int row_l = w * 16 + q4 * 4 + r;
            int col_l = ni * 16 + l15;
            float ev = __builtin_amdgcn_exp2f(sv[ni][r]) * Ls[h][row_l];
            if (col_l <= row_l) acc[ktl][ni][r] += ev;
          }
      } else {
#pragma unroll
        for (int ni = 0; ni < 4; ++ni)
#pragma unroll
          for (int r = 0; r < 4; ++r) {
            int row_l = w * 16 + q4 * 4 + r;
            acc[ktl][ni][r] += __builtin_amdgcn_exp2f(sv[ni][r]) * Ls[h][row_l];
          }
      }
    }
    __syncthreads();     // drains vmcnt; LDS reads done; next K (or V) ready
    cur ^= 1;
    q0 = nq0; q1 = nq1;
  }

  // Tail: V is in Ks[cur] (staged into cur^1 at h=15, then cur flipped).
  // P goes into the OTHER K buffer (head-15's K, reads done at last barrier).
  u16* Vl = &Ks[cur][0][0];
  u16* Pl = &Ks[cur ^ 1][0][0];   // [64][128] bf16 (16KB)

  // write attn f32 + P bf16 (swizzled) to LDS
#pragma unroll
  for (int ktl = 0; ktl < 2; ++ktl)
#pragma unroll
    for (int ni = 0; ni < 4; ++ni)
#pragma unroll
      for (int r = 0; r < 4; ++r) {
        const int row_l = w * 16 + q4 * 4 + r;
        const int col = ktl * 64 + ni * 16 + l15;
        float pv = acc[ktl][ni][r] * 0.0625f;
        outp[(size_t)row_l * T_SZ + col] = pv;
        const int u = ktl * 8 + ni * 2 + (l15 >> 3);
        const int phys = (u & 8) | ((u ^ (row_l & 7)) & 7);
        Pl[row_l * 128 + phys * 8 + (l15 & 7)] = f2bf(pv);
      }
  __syncthreads();

  // ctx partial: D[m][dh] = sum_t P[m][t] * Vt[dh][t]
  f32x4 cacc[4] = {};
#pragma unroll
  for (int kc = 0; kc < 4; ++kc) {
    const int u = kc * 4 + q4;
    const int phys = (u & 8) | ((u ^ (l15 & 7)) & 7);   // row&7 == l15&7 both sides
    s16x8 pa = *(const s16x8*)&Pl[(w * 16 + l15) * 128 + phys * 8];
#pragma unroll
    for (int ni = 0; ni < 4; ++ni) {
      s16x8 vb = *(const s16x8*)&Vl[(ni * 16 + l15) * 128 + phys * 8];
      cacc[ni] = __builtin_amdgcn_mfma_f32_16x16x32_bf16(pa, vb, cacc[ni], 0, 0, 0);
    }
  }
  float* pp = part + ((size_t)iold * B_SZ + b) * (64 * DH);
#pragma unroll
  for (int ni = 0; ni < 4; ++ni)
#pragma unroll
    for (int r = 0; r < 4; ++r)
      pp[(size_t)(w * 16 + q4 * 4 + r) * DH + ni * 16 + l15] = cacc[ni][r];
}

// ---------------------------------------------------------------------------
// V projection -> bf16 V^T: Vt[b][col][t] = bf16((v @ Wv)[b*2048+t][col]).
// One block per 16 rows (256 blocks); transpose through LDS. (R10-verified)
// ---------------------------------------------------------------------------
__global__ __launch_bounds__(256)
void proj_v(const float* __restrict__ A, const float* __restrict__ W,
            u16* __restrict__ Vt) {
  __shared__ float Ws[64][68];
  __shared__ float As[16][68];
  __shared__ float tr[64][17];
  const int tid = threadIdx.x;
  const int m0 = blockIdx.x * 16;
  const int row = tid >> 4;
  const int c4  = tid & 15;
  float4 acc = make_float4(0.f, 0.f, 0.f, 0.f);

  for (int k0 = 0; k0 < DM; k0 += 64) {
    __syncthreads();
#pragma unroll
    for (int e = 0; e < 4; ++e) {
      int lin = tid + e * 256;
      int r = lin >> 4, cc = lin & 15;
      *(float4*)&Ws[r][cc * 4] = *(const float4*)(W + (size_t)(k0 + r) * DH + cc * 4);
    }
    *(float4*)&As[row][c4 * 4] = *(const float4*)(A + (size_t)(m0 + row) * DM + k0 + c4 * 4);
    __syncthreads();
#pragma unroll
    for (int kk = 0; kk < 64; ++kk) {
      float a = As[row][kk];
      float4 wv = *(const float4*)&Ws[kk][c4 * 4];
      acc.x += a * wv.x; acc.y += a * wv.y; acc.z += a * wv.z; acc.w += a * wv.w;
    }
  }
  __syncthreads();
  tr[c4 * 4 + 0][row] = acc.x;
  tr[c4 * 4 + 1][row] = acc.y;
  tr[c4 * 4 + 2][row] = acc.z;
  tr[c4 * 4 + 3][row] = acc.w;
  __syncthreads();
  const int b = m0 >> 11;
  const int t0 = m0 & 2047;
  int col = tid >> 2, tc = tid & 3;
  ushort4 o;
  o.x = f2bf(tr[col][tc * 4 + 0]);
  o.y = f2bf(tr[col][tc * 4 + 1]);
  o.z = f2bf(tr[col][tc * 4 + 2]);
  o.w = f2bf(tr[col][tc * 4 + 3]);
  *(ushort4*)(Vt + ((size_t)b * DH + col) * T_SZ + t0 + tc * 4) = o;
}

// ---------------------------------------------------------------------------
// Dedicated compact-partials reduce (R7-verified): block (mt, b) sums its
// ncc = (mt>>1)+1 chunks -- block-uniform, coalesced, L2-resident.
// ---------------------------------------------------------------------------
__global__ __launch_bounds__(256)
void ctx_reduce(const float* __restrict__ part, float* __restrict__ ctx) {
  const int mt = blockIdx.x, b = blockIdx.y;
  const int sm = (mt + 1) >> 1;
  const int base = (mt & 1) ? sm * sm : sm * (sm + 1);
  const int ncc = (mt >> 1) + 1;
  const int tid = threadIdx.x;

  float4 a[4] = {};
  for (int cc = 0; cc < ncc; ++cc) {
    const float4* p = (const float4*)(part + ((size_t)(base + cc) * B_SZ + b) * (64 * DH));
#pragma unroll
    for (int j = 0; j < 4; ++j) {
      float4 v = p[tid + j * 256];
      a[j].x += v.x; a[j].y += v.y; a[j].z += v.z; a[j].w += v.w;
    }
  }
  float4* dst = (float4*)(ctx + ((size_t)b * T_SZ + (size_t)mt * 64) * DH);
#pragma unroll
  for (int j = 0; j < 4; ++j) dst[tid + j * 256] = a[j];
}

// ---------------------------------------------------------------------------
// Wo projection v2 (R7-verified): dense ctx[4096][64], no reduce loop.
// GRID (32 m, 8 n): blocks sharing the A-band share ID%8 -> same XCD.
// ---------------------------------------------------------------------------
__global__ __launch_bounds__(256)
void gemm_wo(const float* __restrict__ ctx, const float* __restrict__ W,
             float* __restrict__ C) {
  __shared__ float As[16][132];
  __shared__ float Ws[16][132];
  const int tid = threadIdx.x;
  const int tx = tid & 15, ty = tid >> 4;
  const int m0 = blockIdx.x * 128;   // x=m for XCD share
  const int n0 = blockIdx.y * 128;

  float acc[8][8];
#pragma unroll
  for (int i = 0; i < 8; ++i)
#pragma unroll
    for (int j = 0; j < 8; ++j) acc[i][j] = 0.f;

  for (int k0 = 0; k0 < DH; k0 += 16) {
    __syncthreads();
#pragma unroll
    for (int e = 0; e < 2; ++e) {
      int lin = tid + e * 256;
      int i = lin >> 2, j4 = lin & 3;
      float4 p = *(const float4*)(ctx + (size_t)(m0 + i) * DH + k0 + j4 * 4);
      As[j4 * 4 + 0][i] = p.x;
      As[j4 * 4 + 1][i] = p.y;
      As[j4 * 4 + 2][i] = p.z;
      As[j4 * 4 + 3][i] = p.w;
    }
#pragma unroll
    for (int e = 0; e < 2; ++e) {
      int lin = tid + e * 256;
      int kk = lin >> 5, n4 = lin & 31;
      *(float4*)&Ws[kk][n4 * 4] = *(const float4*)(W + (size_t)(k0 + kk) * DM + n0 + n4 * 4);
    }
    __syncthreads();
#pragma unroll
    for (int kk = 0; kk < 16; ++kk) {
      float4 a0 = *(const float4*)&As[kk][ty * 8];
      float4 a1 = *(const float4*)&As[kk][ty * 8 + 4];
      float4 b0 = *(const float4*)&Ws[kk][tx * 8];
      float4 b1 = *(const float4*)&Ws[kk][tx * 8 + 4];
      float a[8] = {a0.x, a0.y, a0.z, a0.w, a1.x, a1.y, a1.z, a1.w};
      float b[8] = {b0.x, b0.y, b0.z, b0.w, b1.x, b1.y, b1.z, b1.w};
#pragma unroll
      for (int i = 0; i < 8; ++i)
#pragma unroll
        for (int j = 0; j < 8; ++j) acc[i][j] += a[i] * b[j];
    }
  }
#pragma unroll
  for (int i = 0; i < 8; ++i) {
    size_t m = (size_t)(m0 + ty * 8 + i);
    int n = n0 + tx * 8;
    *(float4*)(C + m * DM + n) = make_float4(acc[i][0], acc[i][1], acc[i][2], acc[i][3]);
    *(float4*)(C + m * DM + n + 4) = make_float4(acc[i][4], acc[i][5], acc[i][6], acc[i][7]);
  }
}

// ---------------------------------------------------------------------------
extern "C" void kernel_launch(void* const* d_in, const int* in_sizes, int n_in,
                              void* d_out, int out_size, void* d_ws, size_t ws_size,
                              hipStream_t stream) {
  (void)in_sizes; (void)n_in; (void)out_size; (void)ws_size;

  const float* q  = (const float*)d_in[0];
  const float* k  = (const float*)d_in[1];
  const float* v  = (const float*)d_in[2];
  // d_in[3] is the causal tril mask; causality applied analytically.
  const float* Wq = (const float*)d_in[4];
  const float* Wk = (const float*)d_in[5];
  const float* Wv = (const float*)d_in[6];
  const float* Wo = (const float*)d_in[7];

  float* out  = (float*)d_out;                      // [4096][1024]
  float* attn = out + (size_t)MROWS * DM;           // [2][2048][2048]

  // Workspace (~30 MB)
  u16*   Qb   = (u16*)d_ws;                         // [4096][1024] bf16 (Q pre-scaled by 0.125*log2e)
  u16*   Kb   = Qb + (size_t)MROWS * DM;
  u16*   Wqt  = Kb + (size_t)MROWS * DM;            // [1024][1024] bf16 (W^T)
  u16*   Wkt  = Wqt + (size_t)DM * DM;
  u16*   Vt   = Wkt + (size_t)DM * DM;              // [2][64][2048] bf16 (V^T)
  float* invL = (float*)(Vt + (size_t)B_SZ * DH * T_SZ);  // [2][16][2048] f32
  float* part = invL + (size_t)B_SZ * NH * T_SZ;    // [272][2][64][64] f32 (8.9 MB, compact)

  // bf16 copies of q,k live in the attn OUTPUT region as scratch: gemm_qk2
  // consumes them before attn_write overwrites attn (stream-ordered).
  u16* Qc = (u16*)attn;                             // [4096][1024] bf16
  u16* Kc = Qc + (size_t)MROWS * DM;

  // dense ctx [4096][64] f32 (1 MB) aliases Qb: Qb's last readers
  // (attn_sums_v8 / attn_write_v12) precede ctx_reduce in stream order.
  float* ctx = (float*)Qb;

  // partial sums [2][2][16][2048] f32 (512 KB) alias Wqt: Wqt's last reader
  // (gemm_qk2) precedes attn_sums_v8 in stream order.
  float* sumsP = (float*)Wqt;

  dim3 thr(256, 1, 1);

  // Q pre-scaled so prob = exp2(score): scale = 0.125 * log2(e)
  const float qscale = 0.125f * 1.44269504088896340736f;

  cvt_qk<<<dim3(MROWS * DM / (256 * 8), 2), thr, 0, stream>>>(q, k, Qc, Kc, qscale);
  k_cvt_T2<<<dim3(DM / 64, DM / 64, 2), thr, 0, stream>>>(Wq, Wk, Wqt, Wkt);

  gemm_qk2<<<dim3(MROWS / 128, DM / 128, 2), thr, 0, stream>>>(Qc, Kc, Wqt, Wkt, Qb, Kb);
  proj_v<<<MROWS / 16, thr, 0, stream>>>(v, Wv, Vt);

  attn_sums_v8<<<dim3(32, NH, B_SZ), thr, 0, stream>>>(Qb, Kb, sumsP);
  invL_combine<<<dim3(B_SZ * NH * T_SZ / (256 * 4)), thr, 0, stream>>>(sumsP, invL);
  attn_write_v12<<<dim3(1024), thr, 0, stream>>>(Qb, Kb, invL, Vt, attn, part);

  ctx_reduce<<<dim3(T_SZ / 64, B_SZ), thr, 0, stream>>>(part, ctx);
  gemm_wo<<<dim3(MROWS / 128, DM / 128), thr, 0, stream>>>(ctx, Wo, out);
}